// Round 7
// baseline (50901.797 us; speedup 1.0000x reference)
//
#include <hip/hip_runtime.h>

// ============================================================================
// Seq2Seq (bi-LSTM encoder + Bahdanau-attention LSTM decoder) on gfx950.
// fp32 in/out; fp16 internal (fp32 accum/state).
// R7: per-step launches (kernel-boundary sync -- R5/R6 proved in-kernel
// device-scope sync is poison).  Attention = single fused online-softmax
// pass, 256 blocks (b x s-half) writing softmax partials; k_gates prologue
// combines partials (redundant per block, no sync) before the proven GEMM.
// ============================================================================

typedef _Float16 f16;
typedef _Float16 half8 __attribute__((ext_vector_type(8)));
typedef float f32x4 __attribute__((ext_vector_type(4)));

#define MFMA16(a, b, c) __builtin_amdgcn_mfma_f32_16x16x32_f16((a), (b), (c), 0, 0, 0)

__device__ __forceinline__ float fsig(float x) {
    return __builtin_amdgcn_rcpf(1.f + __expf(-x));
}
__device__ __forceinline__ float ftanh(float x) {
    return 1.f - 2.f * __builtin_amdgcn_rcpf(1.f + __expf(2.f * x));
}
__device__ __forceinline__ int frag_idx(int m, int k, int KS) {
    return (((m >> 4) * KS + (k >> 5)) * 64 + (((k >> 3) & 3) * 16 + (m & 15))) * 8 + (k & 7);
}

// ---------------------------------------------------------------------------
// K0: one-shot: pack weights to fragment order (f32 -> f16), plain converts,
// zero out t=0 output row.
// ---------------------------------------------------------------------------
__global__ __launch_bounds__(256) void k_prep(
    const float* __restrict__ attn_W, const float* __restrict__ out_W,
    const float* __restrict__ enc_emb,
    const float* __restrict__ wihf, const float* __restrict__ wihb,
    const float* __restrict__ whhf, const float* __restrict__ whhb,
    const float* __restrict__ dec_emb, const float* __restrict__ dec_wih,
    const float* __restrict__ dec_whh,
    f16* __restrict__ WhT_sw, f16* __restrict__ outWT_sw,
    f16* __restrict__ whhf_sw, f16* __restrict__ whhb_sw,
    f16* __restrict__ decwih_sw, f16* __restrict__ decwhh_sw,
    f16* __restrict__ WeT, f16* __restrict__ emb16,
    f16* __restrict__ wihf16, f16* __restrict__ wihb16,
    f16* __restrict__ decemb16, float* __restrict__ out)
{
    long i = (long)blockIdx.x * 256 + threadIdx.x;
    if (i >= 3784704L) return;
    long idx = i;
    if (idx < 262144) {  // WhT_sw: N=512(e) x K=512(d)
        int j = idx & 7, lane = (idx >> 3) & 63, c = lane & 15, q = lane >> 4;
        int ks = (idx >> 9) & 15, nt = idx >> 13;
        WhT_sw[idx] = (f16)attn_W[(ks * 32 + q * 8 + j) * 512 + nt * 16 + c];
        return;
    }
    idx -= 262144;
    if (idx < 65536) {   // outWT_sw: N=128(v) x K=512(d)
        int j = idx & 7, lane = (idx >> 3) & 63, c = lane & 15, q = lane >> 4;
        int ks = (idx >> 9) & 15, nt = idx >> 13;
        outWT_sw[idx] = (f16)out_W[(ks * 32 + q * 8 + j) * 128 + nt * 16 + c];
        return;
    }
    idx -= 65536;
    if (idx < 262144) {  // whhf_sw: N=1024 x K=256
        int j = idx & 7, lane = (idx >> 3) & 63, c = lane & 15, q = lane >> 4;
        int ks = (idx >> 9) & 7, nt = idx >> 12;
        whhf_sw[idx] = (f16)whhf[(nt * 16 + c) * 256 + ks * 32 + q * 8 + j];
        return;
    }
    idx -= 262144;
    if (idx < 262144) {  // whhb_sw
        int j = idx & 7, lane = (idx >> 3) & 63, c = lane & 15, q = lane >> 4;
        int ks = (idx >> 9) & 7, nt = idx >> 12;
        whhb_sw[idx] = (f16)whhb[(nt * 16 + c) * 256 + ks * 32 + q * 8 + j];
        return;
    }
    idx -= 262144;
    if (idx < 1310720) { // decwih_sw: N=2048 x K=640
        int j = idx & 7, lane = (idx >> 3) & 63, c = lane & 15, q = lane >> 4;
        int r2 = idx >> 9; int ks = r2 % 20, nt = r2 / 20;
        decwih_sw[idx] = (f16)dec_wih[(nt * 16 + c) * 640 + ks * 32 + q * 8 + j];
        return;
    }
    idx -= 1310720;
    if (idx < 1048576) { // decwhh_sw: N=2048 x K=512
        int j = idx & 7, lane = (idx >> 3) & 63, c = lane & 15, q = lane >> 4;
        int ks = (idx >> 9) & 15, nt = idx >> 13;
        decwhh_sw[idx] = (f16)dec_whh[(nt * 16 + c) * 512 + ks * 32 + q * 8 + j];
        return;
    }
    idx -= 1048576;
    if (idx < 262144) { int e = idx >> 9, d = idx & 511; WeT[idx] = (f16)attn_W[(512 + d) * 512 + e]; return; }
    idx -= 262144;
    if (idx < 16384)  { emb16[idx] = (f16)enc_emb[idx]; return; }
    idx -= 16384;
    if (idx < 131072) { wihf16[idx] = (f16)wihf[idx]; return; }
    idx -= 131072;
    if (idx < 131072) { wihb16[idx] = (f16)wihb[idx]; return; }
    idx -= 131072;
    if (idx < 16384)  { decemb16[idx] = (f16)dec_emb[idx]; return; }
    idx -= 16384;
    if (idx < 16384)  { int b = idx >> 7, v = idx & 127; out[b * 16384 + v] = 0.f; return; }
}

// ---------------------------------------------------------------------------
// K_vocab: xg_vocab[v][n] = emb[v] @ [Wih_f|Wih_b]^T + [b_f|b_b] (once).
// ---------------------------------------------------------------------------
__global__ __launch_bounds__(256) void k_vocab(
    const f16* __restrict__ emb, const f16* __restrict__ wihf,
    const f16* __restrict__ wihb, const float* __restrict__ bf_,
    const float* __restrict__ bb_, f16* __restrict__ xg_vocab)
{
    int bn = blockIdx.x;
    int tid = threadIdx.x, wave = tid >> 6, lane = tid & 63;
    int col = lane & 15, quad = lane >> 4;
    int wr = wave >> 1, wc = wave & 1;

    f32x4 acc[4][4] = {};
    for (int ks = 0; ks < 4; ++ks) {
        int k0 = ks * 32 + quad * 8;
        half8 a[4], bfr[4];
        for (int i = 0; i < 4; ++i)
            a[i] = *(const half8*)(emb + (wr * 64 + i * 16 + col) * 128 + k0);
        for (int j = 0; j < 4; ++j) {
            int n = bn * 128 + wc * 64 + j * 16 + col;
            const f16* wp = (n < 1024) ? (wihf + n * 128) : (wihb + (n - 1024) * 128);
            bfr[j] = *(const half8*)(wp + k0);
        }
        for (int i = 0; i < 4; ++i)
            for (int j = 0; j < 4; ++j)
                acc[i][j] = MFMA16(a[i], bfr[j], acc[i][j]);
    }
    for (int j = 0; j < 4; ++j) {
        int n = bn * 128 + wc * 64 + j * 16 + col;
        float bias = (n < 1024) ? bf_[n] : bb_[n - 1024];
        for (int i = 0; i < 4; ++i) {
            int vbase = wr * 64 + i * 16 + quad * 4;
            for (int r = 0; r < 4; ++r)
                xg_vocab[(vbase + r) * 2048 + n] = (f16)(acc[i][j][r] + bias);
        }
    }
}

// ---------------------------------------------------------------------------
// K_enc: encoder scan, 16 persistent blocks (2 dir x 8 batch-groups of 16),
// 512 threads.  (unchanged -- known correct)
// ---------------------------------------------------------------------------
__global__ __launch_bounds__(512) void k_enc(
    const int* __restrict__ src, const f16* __restrict__ xg_vocab,
    const f16* __restrict__ whhf_sw, const f16* __restrict__ whhb_sw,
    f16* __restrict__ enc_out, f16* __restrict__ hdec0, float* __restrict__ c_ws)
{
    int blk = blockIdx.x;
    int dir = blk >> 3, bbase = (blk & 7) * 16;
    int tid = threadIdx.x, wave = tid >> 6, lane = tid & 63;
    int col = lane & 15, quad = lane >> 4;
    const f16* whh = dir ? whhb_sw : whhf_sw;

    __shared__ f16 hb[16][264];
    __shared__ f16 xvb[16][1032];
    __shared__ int stok[16];
    for (int z = tid; z < 16 * 264; z += 512) ((f16*)hb)[z] = (f16)0.f;
    float cc[2][4] = {};
    __syncthreads();

    for (int t = 0; t < 512; ++t) {
        int ts = dir ? (511 - t) : t;
        if (tid < 16) stok[tid] = src[(bbase + tid) * 512 + ts];
        half8 a[8];
        #pragma unroll
        for (int kk = 0; kk < 8; ++kk)
            a[kk] = *(const half8*)(&hb[col][kk * 32 + quad * 8]);
        __syncthreads();

        #pragma unroll
        for (int it = 0; it < 4; ++it) {
            int cnk = it * 512 + tid;
            int row = cnk >> 7, off = (cnk & 127) * 8;
            *(half8*)(&xvb[row][off]) =
                *(const half8*)(xg_vocab + stok[row] * 2048 + dir * 1024 + off);
        }

        f32x4 acc[4][2] = {};
        #pragma unroll
        for (int kk = 0; kk < 8; ++kk) {
            half8 bv[8];
            #pragma unroll
            for (int g = 0; g < 4; ++g)
                #pragma unroll
                for (int nt = 0; nt < 2; ++nt) {
                    int tile = g * 16 + wave * 2 + nt;
                    bv[g * 2 + nt] = *(const half8*)(whh + ((tile * 8 + kk) * 64 + lane) * 8);
                }
            #pragma unroll
            for (int g = 0; g < 4; ++g)
                #pragma unroll
                for (int nt = 0; nt < 2; ++nt)
                    acc[g][nt] = MFMA16(a[kk], bv[g * 2 + nt], acc[g][nt]);
        }
        __syncthreads();

        #pragma unroll
        for (int nt = 0; nt < 2; ++nt) {
            int hcol = wave * 32 + nt * 16 + col;
            #pragma unroll
            for (int r = 0; r < 4; ++r) {
                int b = quad * 4 + r;
                float gi = (float)xvb[b][0 * 256 + hcol] + acc[0][nt][r];
                float gf = (float)xvb[b][1 * 256 + hcol] + acc[1][nt][r];
                float gg = (float)xvb[b][2 * 256 + hcol] + acc[2][nt][r];
                float go = (float)xvb[b][3 * 256 + hcol] + acc[3][nt][r];
                float ig = fsig(gi), fg = fsig(gf), g2 = ftanh(gg), og = fsig(go);
                float cv = fg * cc[nt][r] + ig * g2;
                cc[nt][r] = cv;
                float h = og * ftanh(cv);
                f16 h16 = (f16)h;
                hb[b][hcol] = h16;
                enc_out[((size_t)(bbase + b) * 512 + ts) * 512 + dir * 256 + hcol] = h16;
            }
        }
        __syncthreads();
    }
    #pragma unroll
    for (int nt = 0; nt < 2; ++nt) {
        int hcol = wave * 32 + nt * 16 + col;
        #pragma unroll
        for (int r = 0; r < 4; ++r) {
            int b = quad * 4 + r;
            int m = bbase + b, k = dir * 256 + hcol;
            hdec0[frag_idx(m, k, 16)] = hb[b][hcol];
            c_ws[m * 512 + k] = cc[nt][r];
        }
    }
}

// ---------------------------------------------------------------------------
// K_proj: enc_proj = enc_out @ We (once).
// ---------------------------------------------------------------------------
__global__ __launch_bounds__(256) void k_proj(
    const f16* __restrict__ enc_out, const f16* __restrict__ WeT,
    f16* __restrict__ proj)
{
    int blk = blockIdx.x;
    int bm = blk & 511, bn = blk >> 9;
    int tid = threadIdx.x, wave = tid >> 6, lane = tid & 63;
    int col = lane & 15, quad = lane >> 4;
    int wr = wave >> 1, wc = wave & 1;

    f32x4 acc[4][4] = {};
    for (int ks = 0; ks < 16; ++ks) {
        int k0 = ks * 32 + quad * 8;
        half8 a[4], bfr[4];
        for (int i = 0; i < 4; ++i) {
            int m = bm * 128 + wr * 64 + i * 16 + col;
            a[i] = *(const half8*)(enc_out + (size_t)m * 512 + k0);
        }
        for (int j = 0; j < 4; ++j) {
            int n = bn * 128 + wc * 64 + j * 16 + col;
            bfr[j] = *(const half8*)(WeT + n * 512 + k0);
        }
        for (int i = 0; i < 4; ++i)
            for (int j = 0; j < 4; ++j)
                acc[i][j] = MFMA16(a[i], bfr[j], acc[i][j]);
    }
    for (int j = 0; j < 4; ++j) {
        int n = bn * 128 + wc * 64 + j * 16 + col;
        for (int i = 0; i < 4; ++i) {
            int mbase = bm * 128 + wr * 64 + i * 16 + quad * 4;
            for (int r = 0; r < 4; ++r)
                proj[(size_t)(mbase + r) * 512 + n] = (f16)acc[i][j][r];
        }
    }
}

// ---------------------------------------------------------------------------
// K_qinit: initial q-partials (once).
// ---------------------------------------------------------------------------
__global__ __launch_bounds__(256) void k_qinit(
    const f16* __restrict__ h0_sw, const f16* __restrict__ WhT_sw,
    float* __restrict__ qpart)
{
    int j = blockIdx.x;
    int tid = threadIdx.x, wave = tid >> 6, lane = tid & 63;
    int col = lane & 15, quad = lane >> 4;
    half8 a[2];
    #pragma unroll
    for (int i = 0; i < 2; ++i)
        a[i] = *(const half8*)(h0_sw + (((wave * 2 + i) * 16 + j) * 64 + lane) * 8);
    for (int nt = 0; nt < 32; ++nt) {
        half8 bfr = *(const half8*)(WhT_sw + ((nt * 16 + j) * 64 + lane) * 8);
        f32x4 q0 = {}, q1 = {};
        q0 = MFMA16(a[0], bfr, q0);
        q1 = MFMA16(a[1], bfr, q1);
        #pragma unroll
        for (int r = 0; r < 4; ++r) {
            qpart[(j * 128 + wave * 32 + quad * 4 + r) * 512 + nt * 16 + col] = q0[r];
            qpart[(j * 128 + wave * 32 + 16 + quad * 4 + r) * 512 + nt * 16 + col] = q1[r];
        }
    }
}

// ---------------------------------------------------------------------------
// K_att (per step): 256 blocks x 512 thr; block = (b, sh), sh = s-half.
// Single fused online-softmax pass over 256 s-rows (wave owns 32), streaming
// proj+enc_out double-buffered.  Writes UN-normalized partial (m, l, ctx) to
// global -- NO atomics/fences; the kernel boundary publishes.  sh==0 blocks
// also write the dec_emb rows of x_sw.
// ---------------------------------------------------------------------------
__global__ __launch_bounds__(512) void k_att(
    const f16* __restrict__ proj, const f16* __restrict__ enc_out,
    const float* __restrict__ qpart, const float* __restrict__ attn_b,
    const float* __restrict__ attn_v, const int* __restrict__ trg,
    const f16* __restrict__ decemb, f16* __restrict__ x_sw,
    float* __restrict__ part_m, float* __restrict__ part_l,
    float* __restrict__ part_ctx, int t)
{
    int blk = blockIdx.x;
    int b = blk >> 1, sh = blk & 1;
    int tid = threadIdx.x, wave = tid >> 6, lane = tid & 63;

    __shared__ float q[512];
    __shared__ float ctxred[8][512];
    __shared__ float wm[8], wl[8];

    {   // q = attn_b + sum of 16 qpart slices
        float s = attn_b[tid];
        #pragma unroll
        for (int jj = 0; jj < 16; ++jj) s += qpart[(jj * 128 + b) * 512 + tid];
        q[tid] = s;
    }
    __syncthreads();

    float qreg[8], vreg[8];
    #pragma unroll
    for (int u = 0; u < 8; ++u) {
        qreg[u] = q[lane * 8 + u];
        vreg[u] = attn_v[lane * 8 + u];
    }

    // fused online-softmax over this wave's 32 rows
    int s0 = sh * 256 + wave * 32;
    float m = -__builtin_inff(), l = 0.f;
    float acc8[8] = {};
    half8 pj[2][4], ev[2][4];
    #pragma unroll
    for (int z = 0; z < 4; ++z) {
        size_t row = (size_t)b * 512 + s0 + z;
        pj[0][z] = *(const half8*)(proj + row * 512 + lane * 8);
        ev[0][z] = *(const half8*)(enc_out + row * 512 + lane * 8);
    }
    for (int g = 0; g < 8; ++g) {
        int cur = g & 1;
        if (g < 7) {
            #pragma unroll
            for (int z = 0; z < 4; ++z) {
                size_t row = (size_t)b * 512 + s0 + (g + 1) * 4 + z;
                pj[cur ^ 1][z] = *(const half8*)(proj + row * 512 + lane * 8);
                ev[cur ^ 1][z] = *(const half8*)(enc_out + row * 512 + lane * 8);
            }
        }
        #pragma unroll
        for (int z = 0; z < 4; ++z) {
            float part = 0.f;
            #pragma unroll
            for (int u = 0; u < 8; ++u)
                part += vreg[u] * ftanh(qreg[u] + (float)pj[cur][z][u]);
            #pragma unroll
            for (int o = 32; o; o >>= 1) part += __shfl_xor(part, o);
            float mn = fmaxf(m, part);
            float scale = __expf(m - mn);
            float w = __expf(part - mn);
            l = l * scale + w;
            #pragma unroll
            for (int u = 0; u < 8; ++u)
                acc8[u] = acc8[u] * scale + w * (float)ev[cur][z][u];
            m = mn;
        }
    }
    // combine 8 waves in LDS -> one block partial
    if (lane == 0) { wm[wave] = m; wl[wave] = l; }
    #pragma unroll
    for (int u = 0; u < 8; ++u) ctxred[wave][lane * 8 + u] = acc8[u];
    __syncthreads();
    float mb = wm[0];
    #pragma unroll
    for (int w = 1; w < 8; ++w) mb = fmaxf(mb, wm[w]);
    float lb = 0.f, cp = 0.f;
    #pragma unroll
    for (int w = 0; w < 8; ++w) {
        float fw = __expf(wm[w] - mb);
        lb += fw * wl[w];
        cp += fw * ctxred[w][tid];
    }
    part_ctx[(size_t)blk * 512 + tid] = cp;
    if (tid == 0) { part_m[blk] = mb; part_l[blk] = lb; }

    if (sh == 0 && tid < 128) {
        int tok = trg[b * 128 + t];
        x_sw[frag_idx(b, tid, 20)] = decemb[tok * 128 + tid];
    }
}

// ---------------------------------------------------------------------------
// K_gates (per step): 16 blocks x 512 thr.  Prologue (all 8 waves): combine
// the two softmax partials per b (redundant per block -- benign identical
// writes) into x_sw ctx rows.  Then waves 0-3 run the proven GEMM + in-lane
// LSTM update + fused q-partial GEMM.
// ---------------------------------------------------------------------------
__global__ __launch_bounds__(512) void k_gates(
    const f16* __restrict__ x_sw_c, f16* __restrict__ x_sw,
    const f16* __restrict__ hprev_sw,
    const f16* __restrict__ wih_sw, const f16* __restrict__ whh_sw,
    const float* __restrict__ dec_b, float* __restrict__ c_ws,
    f16* __restrict__ hnext_sw, f16* __restrict__ hhist_sw,
    const f16* __restrict__ WhT_sw, float* __restrict__ qpart,
    const float* __restrict__ part_m, const float* __restrict__ part_l,
    const float* __restrict__ part_ctx, int t)
{
    int j = blockIdx.x;
    int tid = threadIdx.x, wave = tid >> 6, lane = tid & 63;
    int col = lane & 15, quad = lane >> 4;
    __shared__ f16 hsl[128][40];
    __shared__ float gfac[128][2];

    // ---- prologue: combine partials into x_sw ctx rows (k = 128..639) ----
    if (tid < 128) {
        float m0 = part_m[tid * 2], m1 = part_m[tid * 2 + 1];
        float l0 = part_l[tid * 2], l1 = part_l[tid * 2 + 1];
        float M = fmaxf(m0, m1);
        float g0 = __expf(m0 - M), g1 = __expf(m1 - M);
        float inv = 1.f / (g0 * l0 + g1 * l1);
        gfac[tid][0] = g0 * inv;
        gfac[tid][1] = g1 * inv;
    }
    __syncthreads();
    for (int z = tid; z < 65536; z += 512) {
        int bb = z >> 9, d = z & 511;
        float c = gfac[bb][0] * part_ctx[(size_t)(bb * 2 + 0) * 512 + d]
                + gfac[bb][1] * part_ctx[(size_t)(bb * 2 + 1) * 512 + d];
        x_sw[frag_idx(bb, 128 + d, 20)] = (f16)c;
    }
    __syncthreads();
    if (wave >= 4) return;

    // ---- GEMM: gates = [x|h] @ [Wih|Whh]^T ----
    f32x4 acc[2][8] = {};
    for (int ks = 0; ks < 36; ++ks) {
        half8 a[2];
        #pragma unroll
        for (int i = 0; i < 2; ++i) {
            int mtile = wave * 2 + i;
            a[i] = (ks < 20)
                ? *(const half8*)(x_sw_c + ((mtile * 20 + ks) * 64 + lane) * 8)
                : *(const half8*)(hprev_sw + ((mtile * 16 + (ks - 20)) * 64 + lane) * 8);
        }
        half8 bv[8];
        #pragma unroll
        for (int jt = 0; jt < 8; ++jt) {
            int g = jt >> 1, u2 = jt & 1;
            int ntile = g * 32 + j * 2 + u2;
            bv[jt] = (ks < 20)
                ? *(const half8*)(wih_sw + ((ntile * 20 + ks) * 64 + lane) * 8)
                : *(const half8*)(whh_sw + ((ntile * 16 + (ks - 20)) * 64 + lane) * 8);
        }
        #pragma unroll
        for (int jt = 0; jt < 8; ++jt) {
            acc[0][jt] = MFMA16(a[0], bv[jt], acc[0][jt]);
            acc[1][jt] = MFMA16(a[1], bv[jt], acc[1][jt]);
        }
    }
    float bias[8];
    #pragma unroll
    for (int jt = 0; jt < 8; ++jt) {
        int g = jt >> 1, u2 = jt & 1;
        bias[jt] = dec_b[g * 512 + j * 32 + u2 * 16 + col];
    }
    #pragma unroll
    for (int i = 0; i < 2; ++i) {
        #pragma unroll
        for (int r = 0; r < 4; ++r) {
            int bb = wave * 32 + i * 16 + quad * 4 + r;
            #pragma unroll
            for (int u2 = 0; u2 < 2; ++u2) {
                int hl = u2 * 16 + col, hcol = j * 32 + hl;
                float gi = acc[i][0 + u2][r] + bias[0 + u2];
                float gf = acc[i][2 + u2][r] + bias[2 + u2];
                float gg = acc[i][4 + u2][r] + bias[4 + u2];
                float go = acc[i][6 + u2][r] + bias[6 + u2];
                float ig = fsig(gi), fg = fsig(gf), g2 = ftanh(gg), og = fsig(go);
                float cv = fg * c_ws[bb * 512 + hcol] + ig * g2;
                c_ws[bb * 512 + hcol] = cv;
                float h = og * ftanh(cv);
                f16 h16 = (f16)h;
                int fidx = frag_idx(bb, hcol, 16);
                hnext_sw[fidx] = h16;
                hhist_sw[t * 65536 + fidx] = h16;
                hsl[bb][hl] = h16;
            }
        }
    }
    // fused q-partials for next step (wave reads its own hsl rows)
    half8 aq[2];
    #pragma unroll
    for (int i = 0; i < 2; ++i)
        aq[i] = *(const half8*)(&hsl[wave * 32 + i * 16 + col][quad * 8]);
    for (int nt = 0; nt < 32; ++nt) {
        half8 bq = *(const half8*)(WhT_sw + ((nt * 16 + j) * 64 + lane) * 8);
        f32x4 q0 = {}, q1 = {};
        q0 = MFMA16(aq[0], bq, q0);
        q1 = MFMA16(aq[1], bq, q1);
        #pragma unroll
        for (int r = 0; r < 4; ++r) {
            qpart[(j * 128 + wave * 32 + quad * 4 + r) * 512 + nt * 16 + col] = q0[r];
            qpart[(j * 128 + wave * 32 + 16 + quad * 4 + r) * 512 + nt * 16 + col] = q1[r];
        }
    }
}

// ---------------------------------------------------------------------------
// K_logits: batched over all 127 steps (once).
// ---------------------------------------------------------------------------
__global__ __launch_bounds__(256) void k_logits(
    const f16* __restrict__ hhist_sw, const f16* __restrict__ outWT_sw,
    const float* __restrict__ out_b, float* __restrict__ out)
{
    int bt = blockIdx.x;
    int tid = threadIdx.x, wave = tid >> 6, lane = tid & 63;
    int col = lane & 15, quad = lane >> 4;
    f32x4 acc[2][8] = {};
    for (int ks = 0; ks < 16; ++ks) {
        half8 a[2];
        #pragma unroll
        for (int i = 0; i < 2; ++i)
            a[i] = *(const half8*)(hhist_sw + bt * 65536 + (((wave * 2 + i) * 16 + ks) * 64 + lane) * 8);
        half8 bv[8];
        #pragma unroll
        for (int jt = 0; jt < 8; ++jt)
            bv[jt] = *(const half8*)(outWT_sw + ((jt * 16 + ks) * 64 + lane) * 8);
        #pragma unroll
        for (int jt = 0; jt < 8; ++jt) {
            acc[0][jt] = MFMA16(a[0], bv[jt], acc[0][jt]);
            acc[1][jt] = MFMA16(a[1], bv[jt], acc[1][jt]);
        }
    }
    #pragma unroll
    for (int jt = 0; jt < 8; ++jt) {
        float bias = out_b[jt * 16 + col];
        #pragma unroll
        for (int i = 0; i < 2; ++i)
            #pragma unroll
            for (int r = 0; r < 4; ++r) {
                int br = wave * 32 + i * 16 + quad * 4 + r;
                out[br * 16384 + (bt + 1) * 128 + jt * 16 + col] = acc[i][jt][r] + bias;
            }
    }
}

// ---------------------------------------------------------------------------
extern "C" void kernel_launch(void* const* d_in, const int* in_sizes, int n_in,
                              void* d_out, int out_size, void* d_ws, size_t ws_size,
                              hipStream_t stream)
{
    (void)in_sizes; (void)n_in; (void)out_size;
    if (ws_size < 164000000) return;  // clean bail if workspace too small

    const int*   src     = (const int*)d_in[0];
    const int*   trg     = (const int*)d_in[1];
    const float* enc_emb = (const float*)d_in[2];
    const float* wihf    = (const float*)d_in[3];
    const float* whhf    = (const float*)d_in[4];
    const float* bf_     = (const float*)d_in[5];
    const float* wihb    = (const float*)d_in[6];
    const float* whhb    = (const float*)d_in[7];
    const float* bb_     = (const float*)d_in[8];
    const float* dec_emb = (const float*)d_in[9];
    const float* dec_wih = (const float*)d_in[10];
    const float* dec_whh = (const float*)d_in[11];
    const float* dec_b   = (const float*)d_in[12];
    const float* attn_W  = (const float*)d_in[13];
    const float* attn_b  = (const float*)d_in[14];
    const float* attn_v  = (const float*)d_in[15];
    const float* out_W   = (const float*)d_in[16];
    const float* out_b   = (const float*)d_in[17];
    float* out = (float*)d_out;

    char* p = (char*)d_ws;
    auto carve = [&](size_t n) { char* r = p; p += ((n + 255) & ~(size_t)255); return r; };
    f16*   enc_out   = (f16*)  carve(67108864);
    f16*   proj      = (f16*)  carve(67108864);
    f16*   WhT_sw    = (f16*)  carve(524288);
    f16*   WeT       = (f16*)  carve(524288);
    f16*   outWT_sw  = (f16*)  carve(131072);
    f16*   emb16     = (f16*)  carve(32768);
    f16*   wihf16    = (f16*)  carve(262144);
    f16*   wihb16    = (f16*)  carve(262144);
    f16*   whhf_sw   = (f16*)  carve(524288);
    f16*   whhb_sw   = (f16*)  carve(524288);
    f16*   decemb16  = (f16*)  carve(32768);
    f16*   decwih_sw = (f16*)  carve(2621440);
    f16*   decwhh_sw = (f16*)  carve(2097152);
    float* qpart     = (float*)carve(4194304);
    f16*   hdec0     = (f16*)  carve(131072);
    f16*   hdec1     = (f16*)  carve(131072);
    float* c_ws      = (float*)carve(262144);
    f16*   x_sw      = (f16*)  carve(163840);
    f16*   hhist_sw  = (f16*)  carve(16646144);
    f16*   xg_vocab  = (f16*)  carve(524288);
    float* part_m    = (float*)carve(2048);
    float* part_l    = (float*)carve(2048);
    float* part_ctx  = (float*)carve(1048576);

    k_prep<<<14784, 256, 0, stream>>>(attn_W, out_W, enc_emb, wihf, wihb, whhf, whhb,
                                      dec_emb, dec_wih, dec_whh,
                                      WhT_sw, outWT_sw, whhf_sw, whhb_sw,
                                      decwih_sw, decwhh_sw, WeT, emb16,
                                      wihf16, wihb16, decemb16, out);
    k_vocab<<<16, 256, 0, stream>>>(emb16, wihf16, wihb16, bf_, bb_, xg_vocab);
    k_enc<<<16, 512, 0, stream>>>(src, xg_vocab, whhf_sw, whhb_sw, enc_out, hdec0, c_ws);
    k_proj<<<2048, 256, 0, stream>>>(enc_out, WeT, proj);
    k_qinit<<<16, 256, 0, stream>>>(hdec0, WhT_sw, qpart);
    for (int t = 0; t < 127; ++t) {
        k_att<<<256, 512, 0, stream>>>(proj, enc_out, qpart, attn_b, attn_v,
                                       trg, decemb16, x_sw, part_m, part_l,
                                       part_ctx, t);
        f16* hin  = (t & 1) ? hdec1 : hdec0;
        f16* hout = (t & 1) ? hdec0 : hdec1;
        k_gates<<<16, 512, 0, stream>>>(x_sw, x_sw, hin, decwih_sw, decwhh_sw,
                                        dec_b, c_ws, hout, hhist_sw, WhT_sw,
                                        qpart, part_m, part_l, part_ctx, t);
    }
    k_logits<<<127, 256, 0, stream>>>(hhist_sw, outWT_sw, out_b, out);
}

// Round 8
// 13927.478 us; speedup vs baseline: 3.6548x; 3.6548x over previous
//
#include <hip/hip_runtime.h>

// ============================================================================
// Seq2Seq (bi-LSTM encoder + Bahdanau-attention LSTM decoder) on gfx950.
// fp32 in/out; fp16 internal (fp32 accum/state).
// R8 = R4 (measured best, 15.26 ms) + two surgical deltas:
//   (1) k_att ctx pass uses half8 loads (16B/lane, 8-deep) + LDS wave-combine;
//       scores pass batching 4->8.  Two independent-iteration passes kept
//       (online-softmax fusion measurably regressed 3x -- R5/R6/R7).
//   (2) k_gates split 16->32 blocks (m-halves); qpart layout unchanged.
// ============================================================================

typedef _Float16 f16;
typedef _Float16 half8 __attribute__((ext_vector_type(8)));
typedef float f32x4 __attribute__((ext_vector_type(4)));

#define MFMA16(a, b, c) __builtin_amdgcn_mfma_f32_16x16x32_f16((a), (b), (c), 0, 0, 0)

__device__ __forceinline__ float fsig(float x) {
    return __builtin_amdgcn_rcpf(1.f + __expf(-x));
}
__device__ __forceinline__ float ftanh(float x) {
    return 1.f - 2.f * __builtin_amdgcn_rcpf(1.f + __expf(2.f * x));
}
__device__ __forceinline__ int frag_idx(int m, int k, int KS) {
    return (((m >> 4) * KS + (k >> 5)) * 64 + (((k >> 3) & 3) * 16 + (m & 15))) * 8 + (k & 7);
}

// ---------------------------------------------------------------------------
// K0: one-shot: pack weights to fragment order (f32 -> f16), plain converts,
// zero out t=0 output row.
// ---------------------------------------------------------------------------
__global__ __launch_bounds__(256) void k_prep(
    const float* __restrict__ attn_W, const float* __restrict__ out_W,
    const float* __restrict__ enc_emb,
    const float* __restrict__ wihf, const float* __restrict__ wihb,
    const float* __restrict__ whhf, const float* __restrict__ whhb,
    const float* __restrict__ dec_emb, const float* __restrict__ dec_wih,
    const float* __restrict__ dec_whh,
    f16* __restrict__ WhT_sw, f16* __restrict__ outWT_sw,
    f16* __restrict__ whhf_sw, f16* __restrict__ whhb_sw,
    f16* __restrict__ decwih_sw, f16* __restrict__ decwhh_sw,
    f16* __restrict__ WeT, f16* __restrict__ emb16,
    f16* __restrict__ wihf16, f16* __restrict__ wihb16,
    f16* __restrict__ decemb16, float* __restrict__ out)
{
    long i = (long)blockIdx.x * 256 + threadIdx.x;
    if (i >= 3784704L) return;
    long idx = i;
    if (idx < 262144) {  // WhT_sw: N=512(e) x K=512(d)
        int j = idx & 7, lane = (idx >> 3) & 63, c = lane & 15, q = lane >> 4;
        int ks = (idx >> 9) & 15, nt = idx >> 13;
        WhT_sw[idx] = (f16)attn_W[(ks * 32 + q * 8 + j) * 512 + nt * 16 + c];
        return;
    }
    idx -= 262144;
    if (idx < 65536) {   // outWT_sw: N=128(v) x K=512(d)
        int j = idx & 7, lane = (idx >> 3) & 63, c = lane & 15, q = lane >> 4;
        int ks = (idx >> 9) & 15, nt = idx >> 13;
        outWT_sw[idx] = (f16)out_W[(ks * 32 + q * 8 + j) * 128 + nt * 16 + c];
        return;
    }
    idx -= 65536;
    if (idx < 262144) {  // whhf_sw: N=1024 x K=256
        int j = idx & 7, lane = (idx >> 3) & 63, c = lane & 15, q = lane >> 4;
        int ks = (idx >> 9) & 7, nt = idx >> 12;
        whhf_sw[idx] = (f16)whhf[(nt * 16 + c) * 256 + ks * 32 + q * 8 + j];
        return;
    }
    idx -= 262144;
    if (idx < 262144) {  // whhb_sw
        int j = idx & 7, lane = (idx >> 3) & 63, c = lane & 15, q = lane >> 4;
        int ks = (idx >> 9) & 7, nt = idx >> 12;
        whhb_sw[idx] = (f16)whhb[(nt * 16 + c) * 256 + ks * 32 + q * 8 + j];
        return;
    }
    idx -= 262144;
    if (idx < 1310720) { // decwih_sw: N=2048 x K=640
        int j = idx & 7, lane = (idx >> 3) & 63, c = lane & 15, q = lane >> 4;
        int r2 = idx >> 9; int ks = r2 % 20, nt = r2 / 20;
        decwih_sw[idx] = (f16)dec_wih[(nt * 16 + c) * 640 + ks * 32 + q * 8 + j];
        return;
    }
    idx -= 1310720;
    if (idx < 1048576) { // decwhh_sw: N=2048 x K=512
        int j = idx & 7, lane = (idx >> 3) & 63, c = lane & 15, q = lane >> 4;
        int ks = (idx >> 9) & 15, nt = idx >> 13;
        decwhh_sw[idx] = (f16)dec_whh[(nt * 16 + c) * 512 + ks * 32 + q * 8 + j];
        return;
    }
    idx -= 1048576;
    if (idx < 262144) { int e = idx >> 9, d = idx & 511; WeT[idx] = (f16)attn_W[(512 + d) * 512 + e]; return; }
    idx -= 262144;
    if (idx < 16384)  { emb16[idx] = (f16)enc_emb[idx]; return; }
    idx -= 16384;
    if (idx < 131072) { wihf16[idx] = (f16)wihf[idx]; return; }
    idx -= 131072;
    if (idx < 131072) { wihb16[idx] = (f16)wihb[idx]; return; }
    idx -= 131072;
    if (idx < 16384)  { decemb16[idx] = (f16)dec_emb[idx]; return; }
    idx -= 16384;
    if (idx < 16384)  { int b = idx >> 7, v = idx & 127; out[b * 16384 + v] = 0.f; return; }
}

// ---------------------------------------------------------------------------
// K_vocab: xg_vocab[v][n] = emb[v] @ [Wih_f|Wih_b]^T + [b_f|b_b] (once).
// ---------------------------------------------------------------------------
__global__ __launch_bounds__(256) void k_vocab(
    const f16* __restrict__ emb, const f16* __restrict__ wihf,
    const f16* __restrict__ wihb, const float* __restrict__ bf_,
    const float* __restrict__ bb_, f16* __restrict__ xg_vocab)
{
    int bn = blockIdx.x;
    int tid = threadIdx.x, wave = tid >> 6, lane = tid & 63;
    int col = lane & 15, quad = lane >> 4;
    int wr = wave >> 1, wc = wave & 1;

    f32x4 acc[4][4] = {};
    for (int ks = 0; ks < 4; ++ks) {
        int k0 = ks * 32 + quad * 8;
        half8 a[4], bfr[4];
        for (int i = 0; i < 4; ++i)
            a[i] = *(const half8*)(emb + (wr * 64 + i * 16 + col) * 128 + k0);
        for (int j = 0; j < 4; ++j) {
            int n = bn * 128 + wc * 64 + j * 16 + col;
            const f16* wp = (n < 1024) ? (wihf + n * 128) : (wihb + (n - 1024) * 128);
            bfr[j] = *(const half8*)(wp + k0);
        }
        for (int i = 0; i < 4; ++i)
            for (int j = 0; j < 4; ++j)
                acc[i][j] = MFMA16(a[i], bfr[j], acc[i][j]);
    }
    for (int j = 0; j < 4; ++j) {
        int n = bn * 128 + wc * 64 + j * 16 + col;
        float bias = (n < 1024) ? bf_[n] : bb_[n - 1024];
        for (int i = 0; i < 4; ++i) {
            int vbase = wr * 64 + i * 16 + quad * 4;
            for (int r = 0; r < 4; ++r)
                xg_vocab[(vbase + r) * 2048 + n] = (f16)(acc[i][j][r] + bias);
        }
    }
}

// ---------------------------------------------------------------------------
// K_enc: encoder scan, 16 persistent blocks (2 dir x 8 batch-groups of 16),
// 512 threads.  (unchanged -- known correct)
// ---------------------------------------------------------------------------
__global__ __launch_bounds__(512) void k_enc(
    const int* __restrict__ src, const f16* __restrict__ xg_vocab,
    const f16* __restrict__ whhf_sw, const f16* __restrict__ whhb_sw,
    f16* __restrict__ enc_out, f16* __restrict__ hdec0, float* __restrict__ c_ws)
{
    int blk = blockIdx.x;
    int dir = blk >> 3, bbase = (blk & 7) * 16;
    int tid = threadIdx.x, wave = tid >> 6, lane = tid & 63;
    int col = lane & 15, quad = lane >> 4;
    const f16* whh = dir ? whhb_sw : whhf_sw;

    __shared__ f16 hb[16][264];
    __shared__ f16 xvb[16][1032];
    __shared__ int stok[16];
    for (int z = tid; z < 16 * 264; z += 512) ((f16*)hb)[z] = (f16)0.f;
    float cc[2][4] = {};
    __syncthreads();

    for (int t = 0; t < 512; ++t) {
        int ts = dir ? (511 - t) : t;
        if (tid < 16) stok[tid] = src[(bbase + tid) * 512 + ts];
        half8 a[8];
        #pragma unroll
        for (int kk = 0; kk < 8; ++kk)
            a[kk] = *(const half8*)(&hb[col][kk * 32 + quad * 8]);
        __syncthreads();

        #pragma unroll
        for (int it = 0; it < 4; ++it) {
            int cnk = it * 512 + tid;
            int row = cnk >> 7, off = (cnk & 127) * 8;
            *(half8*)(&xvb[row][off]) =
                *(const half8*)(xg_vocab + stok[row] * 2048 + dir * 1024 + off);
        }

        f32x4 acc[4][2] = {};
        #pragma unroll
        for (int kk = 0; kk < 8; ++kk) {
            half8 bv[8];
            #pragma unroll
            for (int g = 0; g < 4; ++g)
                #pragma unroll
                for (int nt = 0; nt < 2; ++nt) {
                    int tile = g * 16 + wave * 2 + nt;
                    bv[g * 2 + nt] = *(const half8*)(whh + ((tile * 8 + kk) * 64 + lane) * 8);
                }
            #pragma unroll
            for (int g = 0; g < 4; ++g)
                #pragma unroll
                for (int nt = 0; nt < 2; ++nt)
                    acc[g][nt] = MFMA16(a[kk], bv[g * 2 + nt], acc[g][nt]);
        }
        __syncthreads();

        #pragma unroll
        for (int nt = 0; nt < 2; ++nt) {
            int hcol = wave * 32 + nt * 16 + col;
            #pragma unroll
            for (int r = 0; r < 4; ++r) {
                int b = quad * 4 + r;
                float gi = (float)xvb[b][0 * 256 + hcol] + acc[0][nt][r];
                float gf = (float)xvb[b][1 * 256 + hcol] + acc[1][nt][r];
                float gg = (float)xvb[b][2 * 256 + hcol] + acc[2][nt][r];
                float go = (float)xvb[b][3 * 256 + hcol] + acc[3][nt][r];
                float ig = fsig(gi), fg = fsig(gf), g2 = ftanh(gg), og = fsig(go);
                float cv = fg * cc[nt][r] + ig * g2;
                cc[nt][r] = cv;
                float h = og * ftanh(cv);
                f16 h16 = (f16)h;
                hb[b][hcol] = h16;
                enc_out[((size_t)(bbase + b) * 512 + ts) * 512 + dir * 256 + hcol] = h16;
            }
        }
        __syncthreads();
    }
    #pragma unroll
    for (int nt = 0; nt < 2; ++nt) {
        int hcol = wave * 32 + nt * 16 + col;
        #pragma unroll
        for (int r = 0; r < 4; ++r) {
            int b = quad * 4 + r;
            int m = bbase + b, k = dir * 256 + hcol;
            hdec0[frag_idx(m, k, 16)] = hb[b][hcol];
            c_ws[m * 512 + k] = cc[nt][r];
        }
    }
}

// ---------------------------------------------------------------------------
// K_proj: enc_proj = enc_out @ We (once).
// ---------------------------------------------------------------------------
__global__ __launch_bounds__(256) void k_proj(
    const f16* __restrict__ enc_out, const f16* __restrict__ WeT,
    f16* __restrict__ proj)
{
    int blk = blockIdx.x;
    int bm = blk & 511, bn = blk >> 9;
    int tid = threadIdx.x, wave = tid >> 6, lane = tid & 63;
    int col = lane & 15, quad = lane >> 4;
    int wr = wave >> 1, wc = wave & 1;

    f32x4 acc[4][4] = {};
    for (int ks = 0; ks < 16; ++ks) {
        int k0 = ks * 32 + quad * 8;
        half8 a[4], bfr[4];
        for (int i = 0; i < 4; ++i) {
            int m = bm * 128 + wr * 64 + i * 16 + col;
            a[i] = *(const half8*)(enc_out + (size_t)m * 512 + k0);
        }
        for (int j = 0; j < 4; ++j) {
            int n = bn * 128 + wc * 64 + j * 16 + col;
            bfr[j] = *(const half8*)(WeT + n * 512 + k0);
        }
        for (int i = 0; i < 4; ++i)
            for (int j = 0; j < 4; ++j)
                acc[i][j] = MFMA16(a[i], bfr[j], acc[i][j]);
    }
    for (int j = 0; j < 4; ++j) {
        int n = bn * 128 + wc * 64 + j * 16 + col;
        for (int i = 0; i < 4; ++i) {
            int mbase = bm * 128 + wr * 64 + i * 16 + quad * 4;
            for (int r = 0; r < 4; ++r)
                proj[(size_t)(mbase + r) * 512 + n] = (f16)acc[i][j][r];
        }
    }
}

// ---------------------------------------------------------------------------
// K_qinit: initial q-partials (once).  (unchanged; qpart layout unchanged)
// ---------------------------------------------------------------------------
__global__ __launch_bounds__(256) void k_qinit(
    const f16* __restrict__ h0_sw, const f16* __restrict__ WhT_sw,
    float* __restrict__ qpart)
{
    int j = blockIdx.x;
    int tid = threadIdx.x, wave = tid >> 6, lane = tid & 63;
    int col = lane & 15, quad = lane >> 4;
    half8 a[2];
    #pragma unroll
    for (int i = 0; i < 2; ++i)
        a[i] = *(const half8*)(h0_sw + (((wave * 2 + i) * 16 + j) * 64 + lane) * 8);
    for (int nt = 0; nt < 32; ++nt) {
        half8 bfr = *(const half8*)(WhT_sw + ((nt * 16 + j) * 64 + lane) * 8);
        f32x4 q0 = {}, q1 = {};
        q0 = MFMA16(a[0], bfr, q0);
        q1 = MFMA16(a[1], bfr, q1);
        #pragma unroll
        for (int r = 0; r < 4; ++r) {
            qpart[(j * 128 + wave * 32 + quad * 4 + r) * 512 + nt * 16 + col] = q0[r];
            qpart[(j * 128 + wave * 32 + 16 + quad * 4 + r) * 512 + nt * 16 + col] = q1[r];
        }
    }
}

// ---------------------------------------------------------------------------
// K_att (per step): one block (512 thr) per batch row.  R4 structure:
// scores pass (independent iters, now 8-deep) -> plain softmax -> ctx pass
// (NEW: half8 loads, wave owns s%8, lane owns d=lane*8..+8, LDS combine).
// ---------------------------------------------------------------------------
__global__ __launch_bounds__(512) void k_att(
    const f16* __restrict__ proj, const f16* __restrict__ enc_out,
    const float* __restrict__ qpart, const float* __restrict__ attn_b,
    const float* __restrict__ attn_v, const int* __restrict__ trg,
    const f16* __restrict__ dec_emb, f16* __restrict__ x_sw, int t)
{
    int b = blockIdx.x;
    int tid = threadIdx.x, wave = tid >> 6, lane = tid & 63;
    __shared__ float q[512];
    __shared__ float sc[512];
    __shared__ float ctxred[8][512];
    __shared__ float wred[8], wred2[8];

    {
        float s = attn_b[tid];
        #pragma unroll
        for (int jj = 0; jj < 16; ++jj) s += qpart[(jj * 128 + b) * 512 + tid];
        q[tid] = s;
    }
    __syncthreads();

    float qreg[8], vreg[8];
    #pragma unroll
    for (int u = 0; u < 8; ++u) {
        int e = lane * 8 + u;
        qreg[u] = q[e];
        vreg[u] = attn_v[e];
    }
    // scores: wave w handles s = z8*8 + w; 8-deep load batching
    for (int ib = 0; ib < 8; ++ib) {
        half8 p[8];
        #pragma unroll
        for (int z = 0; z < 8; ++z) {
            int s = (ib * 8 + z) * 8 + wave;
            p[z] = *(const half8*)(proj + ((size_t)b * 512 + s) * 512 + lane * 8);
        }
        #pragma unroll
        for (int z = 0; z < 8; ++z) {
            int s = (ib * 8 + z) * 8 + wave;
            float part = 0.f;
            #pragma unroll
            for (int u = 0; u < 8; ++u)
                part += vreg[u] * ftanh(qreg[u] + (float)p[z][u]);
            #pragma unroll
            for (int o = 32; o; o >>= 1) part += __shfl_xor(part, o);
            if (lane == 0) sc[s] = part;
        }
    }
    __syncthreads();

    // softmax over 512 (one value per thread)
    float s0 = sc[tid];
    float mv = s0;
    #pragma unroll
    for (int o = 32; o; o >>= 1) mv = fmaxf(mv, __shfl_xor(mv, o));
    if (lane == 0) wred[wave] = mv;
    __syncthreads();
    float M = wred[0];
    #pragma unroll
    for (int w = 1; w < 8; ++w) M = fmaxf(M, wred[w]);
    float e0 = __expf(s0 - M);
    float sm = e0;
    #pragma unroll
    for (int o = 32; o; o >>= 1) sm += __shfl_xor(sm, o);
    if (lane == 0) wred2[wave] = sm;
    __syncthreads();
    float den = wred2[0];
    #pragma unroll
    for (int w = 1; w < 8; ++w) den += wred2[w];
    sc[tid] = e0 * (1.f / den);
    __syncthreads();

    // ctx: wave owns s = k*8 + wave; lane owns d = lane*8..+8; 8-deep batch
    float a8[8] = {};
    for (int ib = 0; ib < 8; ++ib) {
        half8 ev[8];
        float wgt[8];
        #pragma unroll
        for (int z = 0; z < 8; ++z) {
            int s = (ib * 8 + z) * 8 + wave;
            ev[z] = *(const half8*)(enc_out + ((size_t)b * 512 + s) * 512 + lane * 8);
            wgt[z] = sc[s];
        }
        #pragma unroll
        for (int z = 0; z < 8; ++z)
            #pragma unroll
            for (int u = 0; u < 8; ++u) a8[u] += wgt[z] * (float)ev[z][u];
    }
    #pragma unroll
    for (int u = 0; u < 8; ++u) ctxred[wave][lane * 8 + u] = a8[u];
    __syncthreads();
    float ctx = 0.f;
    #pragma unroll
    for (int w = 0; w < 8; ++w) ctx += ctxred[w][tid];

    int tok = trg[b * 128 + t];
    if (tid < 128) x_sw[frag_idx(b, tid, 20)] = dec_emb[tok * 128 + tid];
    x_sw[frag_idx(b, 128 + tid, 20)] = (f16)ctx;
}

// ---------------------------------------------------------------------------
// K_gates (per step): 32 blocks = (j n-slice, mh m-half).  Block handles 64
// batch rows x the matched n-slices {g*512 + j*32 .. +32}.  Otherwise the
// proven R4 body; qpart layout unchanged.
// ---------------------------------------------------------------------------
__global__ __launch_bounds__(256) void k_gates(
    const f16* __restrict__ x_sw, const f16* __restrict__ hprev_sw,
    const f16* __restrict__ wih_sw, const f16* __restrict__ whh_sw,
    const float* __restrict__ dec_b, float* __restrict__ c_ws,
    f16* __restrict__ hnext_sw, f16* __restrict__ hhist_sw,
    const f16* __restrict__ WhT_sw, float* __restrict__ qpart, int t)
{
    int jb = blockIdx.x;
    int j = jb >> 1, mh = jb & 1;
    int tid = threadIdx.x, wave = tid >> 6, lane = tid & 63;
    int col = lane & 15, quad = lane >> 4;
    __shared__ f16 hsl[64][40];   // this block's 64 rows x 32-col h-slice

    f32x4 acc[8] = {};   // [jt], jt = g*2+u
    for (int ks = 0; ks < 36; ++ks) {
        int mtile = mh * 4 + wave;
        half8 a = (ks < 20)
            ? *(const half8*)(x_sw + ((mtile * 20 + ks) * 64 + lane) * 8)
            : *(const half8*)(hprev_sw + ((mtile * 16 + (ks - 20)) * 64 + lane) * 8);
        half8 bv[8];
        #pragma unroll
        for (int jt = 0; jt < 8; ++jt) {
            int g = jt >> 1, u2 = jt & 1;
            int ntile = g * 32 + j * 2 + u2;
            bv[jt] = (ks < 20)
                ? *(const half8*)(wih_sw + ((ntile * 20 + ks) * 64 + lane) * 8)
                : *(const half8*)(whh_sw + ((ntile * 16 + (ks - 20)) * 64 + lane) * 8);
        }
        #pragma unroll
        for (int jt = 0; jt < 8; ++jt)
            acc[jt] = MFMA16(a, bv[jt], acc[jt]);
    }
    float bias[8];
    #pragma unroll
    for (int jt = 0; jt < 8; ++jt) {
        int g = jt >> 1, u2 = jt & 1;
        bias[jt] = dec_b[g * 512 + j * 32 + u2 * 16 + col];
    }
    #pragma unroll
    for (int r = 0; r < 4; ++r) {
        int lb = wave * 16 + quad * 4 + r;   // local row 0..63
        int bb = mh * 64 + lb;               // global batch row
        #pragma unroll
        for (int u2 = 0; u2 < 2; ++u2) {
            int hl = u2 * 16 + col, hcol = j * 32 + hl;
            float gi = acc[0 + u2][r] + bias[0 + u2];
            float gf = acc[2 + u2][r] + bias[2 + u2];
            float gg = acc[4 + u2][r] + bias[4 + u2];
            float go = acc[6 + u2][r] + bias[6 + u2];
            float ig = fsig(gi), fg = fsig(gf), g2 = ftanh(gg), og = fsig(go);
            float cv = fg * c_ws[bb * 512 + hcol] + ig * g2;
            c_ws[bb * 512 + hcol] = cv;
            float h = og * ftanh(cv);
            f16 h16 = (f16)h;
            int fidx = frag_idx(bb, hcol, 16);
            hnext_sw[fidx] = h16;
            hhist_sw[t * 65536 + fidx] = h16;
            hsl[lb][hl] = h16;   // same-wave rows only -> no barrier needed
        }
    }
    // fused q-partials for next step (wave reads its own hsl rows)
    half8 aq = *(const half8*)(&hsl[wave * 16 + col][quad * 8]);
    for (int nt = 0; nt < 32; ++nt) {
        half8 bq = *(const half8*)(WhT_sw + ((nt * 16 + j) * 64 + lane) * 8);
        f32x4 q0 = {};
        q0 = MFMA16(aq, bq, q0);
        #pragma unroll
        for (int r = 0; r < 4; ++r)
            qpart[(j * 128 + mh * 64 + wave * 16 + quad * 4 + r) * 512 + nt * 16 + col] = q0[r];
    }
}

// ---------------------------------------------------------------------------
// K_logits: batched over all 127 steps (once).
// ---------------------------------------------------------------------------
__global__ __launch_bounds__(256) void k_logits(
    const f16* __restrict__ hhist_sw, const f16* __restrict__ outWT_sw,
    const float* __restrict__ out_b, float* __restrict__ out)
{
    int bt = blockIdx.x;
    int tid = threadIdx.x, wave = tid >> 6, lane = tid & 63;
    int col = lane & 15, quad = lane >> 4;
    f32x4 acc[2][8] = {};
    for (int ks = 0; ks < 16; ++ks) {
        half8 a[2];
        #pragma unroll
        for (int i = 0; i < 2; ++i)
            a[i] = *(const half8*)(hhist_sw + bt * 65536 + (((wave * 2 + i) * 16 + ks) * 64 + lane) * 8);
        half8 bv[8];
        #pragma unroll
        for (int jt = 0; jt < 8; ++jt)
            bv[jt] = *(const half8*)(outWT_sw + ((jt * 16 + ks) * 64 + lane) * 8);
        #pragma unroll
        for (int jt = 0; jt < 8; ++jt) {
            acc[0][jt] = MFMA16(a[0], bv[jt], acc[0][jt]);
            acc[1][jt] = MFMA16(a[1], bv[jt], acc[1][jt]);
        }
    }
    #pragma unroll
    for (int jt = 0; jt < 8; ++jt) {
        float bias = out_b[jt * 16 + col];
        #pragma unroll
        for (int i = 0; i < 2; ++i)
            #pragma unroll
            for (int r = 0; r < 4; ++r) {
                int br = wave * 32 + i * 16 + quad * 4 + r;
                out[br * 16384 + (bt + 1) * 128 + jt * 16 + col] = acc[i][jt][r] + bias;
            }
    }
}

// ---------------------------------------------------------------------------
extern "C" void kernel_launch(void* const* d_in, const int* in_sizes, int n_in,
                              void* d_out, int out_size, void* d_ws, size_t ws_size,
                              hipStream_t stream)
{
    (void)in_sizes; (void)n_in; (void)out_size;
    if (ws_size < 164000000) return;  // clean bail if workspace too small

    const int*   src     = (const int*)d_in[0];
    const int*   trg     = (const int*)d_in[1];
    const float* enc_emb = (const float*)d_in[2];
    const float* wihf    = (const float*)d_in[3];
    const float* whhf    = (const float*)d_in[4];
    const float* bf_     = (const float*)d_in[5];
    const float* wihb    = (const float*)d_in[6];
    const float* whhb    = (const float*)d_in[7];
    const float* bb_     = (const float*)d_in[8];
    const float* dec_emb = (const float*)d_in[9];
    const float* dec_wih = (const float*)d_in[10];
    const float* dec_whh = (const float*)d_in[11];
    const float* dec_b   = (const float*)d_in[12];
    const float* attn_W  = (const float*)d_in[13];
    const float* attn_b  = (const float*)d_in[14];
    const float* attn_v  = (const float*)d_in[15];
    const float* out_W   = (const float*)d_in[16];
    const float* out_b   = (const float*)d_in[17];
    float* out = (float*)d_out;

    char* p = (char*)d_ws;
    auto carve = [&](size_t n) { char* r = p; p += ((n + 255) & ~(size_t)255); return r; };
    f16*   enc_out   = (f16*)  carve(67108864);
    f16*   proj      = (f16*)  carve(67108864);
    f16*   WhT_sw    = (f16*)  carve(524288);
    f16*   WeT       = (f16*)  carve(524288);
    f16*   outWT_sw  = (f16*)  carve(131072);
    f16*   emb16     = (f16*)  carve(32768);
    f16*   wihf16    = (f16*)  carve(262144);
    f16*   wihb16    = (f16*)  carve(262144);
    f16*   whhf_sw   = (f16*)  carve(524288);
    f16*   whhb_sw   = (f16*)  carve(524288);
    f16*   decemb16  = (f16*)  carve(32768);
    f16*   decwih_sw = (f16*)  carve(2621440);
    f16*   decwhh_sw = (f16*)  carve(2097152);
    float* qpart     = (float*)carve(4194304);
    f16*   hdec0     = (f16*)  carve(131072);
    f16*   hdec1     = (f16*)  carve(131072);
    float* c_ws      = (float*)carve(262144);
    f16*   x_sw      = (f16*)  carve(163840);
    f16*   hhist_sw  = (f16*)  carve(16646144);
    f16*   xg_vocab  = (f16*)  carve(524288);

    k_prep<<<14784, 256, 0, stream>>>(attn_W, out_W, enc_emb, wihf, wihb, whhf, whhb,
                                      dec_emb, dec_wih, dec_whh,
                                      WhT_sw, outWT_sw, whhf_sw, whhb_sw,
                                      decwih_sw, decwhh_sw, WeT, emb16,
                                      wihf16, wihb16, decemb16, out);
    k_vocab<<<16, 256, 0, stream>>>(emb16, wihf16, wihb16, bf_, bb_, xg_vocab);
    k_enc<<<16, 512, 0, stream>>>(src, xg_vocab, whhf_sw, whhb_sw, enc_out, hdec0, c_ws);
    k_proj<<<2048, 256, 0, stream>>>(enc_out, WeT, proj);
    k_qinit<<<16, 256, 0, stream>>>(hdec0, WhT_sw, qpart);
    for (int t = 0; t < 127; ++t) {
        k_att<<<128, 512, 0, stream>>>(proj, enc_out, qpart, attn_b, attn_v,
                                       trg, decemb16, x_sw, t);
        f16* hin  = (t & 1) ? hdec1 : hdec0;
        f16* hout = (t & 1) ? hdec0 : hdec1;
        k_gates<<<32, 256, 0, stream>>>(x_sw, hin, decwih_sw, decwhh_sw, dec_b,
                                        c_ws, hout, hhist_sw, WhT_sw, qpart, t);
    }
    k_logits<<<127, 256, 0, stream>>>(hhist_sw, outWT_sw, out_b, out);
}

// Round 9
// 13599.010 us; speedup vs baseline: 3.7431x; 1.0242x over previous
//
#include <hip/hip_runtime.h>

// ============================================================================
// Seq2Seq (bi-LSTM encoder + Bahdanau-attention LSTM decoder) on gfx950.
// fp32 in/out; fp16 internal (fp32 accum/state).
// R9 = R8 (13.93 ms) + attention concurrency 2x:
//   k_att: 256 blocks (b x s-half), R8's proven two-pass shape per block,
//   writes unnormalized softmax partial (M, l, ctx) -- kernel boundary syncs.
//   k_gates: prologue combines the 2 partials for its own 64 rows into x_sw
//   (identical redundant writes across same-mh blocks -- benign, self-read).
// ============================================================================

typedef _Float16 f16;
typedef _Float16 half8 __attribute__((ext_vector_type(8)));
typedef float f32x4 __attribute__((ext_vector_type(4)));

#define MFMA16(a, b, c) __builtin_amdgcn_mfma_f32_16x16x32_f16((a), (b), (c), 0, 0, 0)

__device__ __forceinline__ float fsig(float x) {
    return __builtin_amdgcn_rcpf(1.f + __expf(-x));
}
__device__ __forceinline__ float ftanh(float x) {
    return 1.f - 2.f * __builtin_amdgcn_rcpf(1.f + __expf(2.f * x));
}
__device__ __forceinline__ int frag_idx(int m, int k, int KS) {
    return (((m >> 4) * KS + (k >> 5)) * 64 + (((k >> 3) & 3) * 16 + (m & 15))) * 8 + (k & 7);
}

// ---------------------------------------------------------------------------
// K0: one-shot: pack weights to fragment order (f32 -> f16), plain converts,
// zero out t=0 output row.
// ---------------------------------------------------------------------------
__global__ __launch_bounds__(256) void k_prep(
    const float* __restrict__ attn_W, const float* __restrict__ out_W,
    const float* __restrict__ enc_emb,
    const float* __restrict__ wihf, const float* __restrict__ wihb,
    const float* __restrict__ whhf, const float* __restrict__ whhb,
    const float* __restrict__ dec_emb, const float* __restrict__ dec_wih,
    const float* __restrict__ dec_whh,
    f16* __restrict__ WhT_sw, f16* __restrict__ outWT_sw,
    f16* __restrict__ whhf_sw, f16* __restrict__ whhb_sw,
    f16* __restrict__ decwih_sw, f16* __restrict__ decwhh_sw,
    f16* __restrict__ WeT, f16* __restrict__ emb16,
    f16* __restrict__ wihf16, f16* __restrict__ wihb16,
    f16* __restrict__ decemb16, float* __restrict__ out)
{
    long i = (long)blockIdx.x * 256 + threadIdx.x;
    if (i >= 3784704L) return;
    long idx = i;
    if (idx < 262144) {  // WhT_sw: N=512(e) x K=512(d)
        int j = idx & 7, lane = (idx >> 3) & 63, c = lane & 15, q = lane >> 4;
        int ks = (idx >> 9) & 15, nt = idx >> 13;
        WhT_sw[idx] = (f16)attn_W[(ks * 32 + q * 8 + j) * 512 + nt * 16 + c];
        return;
    }
    idx -= 262144;
    if (idx < 65536) {   // outWT_sw: N=128(v) x K=512(d)
        int j = idx & 7, lane = (idx >> 3) & 63, c = lane & 15, q = lane >> 4;
        int ks = (idx >> 9) & 15, nt = idx >> 13;
        outWT_sw[idx] = (f16)out_W[(ks * 32 + q * 8 + j) * 128 + nt * 16 + c];
        return;
    }
    idx -= 65536;
    if (idx < 262144) {  // whhf_sw: N=1024 x K=256
        int j = idx & 7, lane = (idx >> 3) & 63, c = lane & 15, q = lane >> 4;
        int ks = (idx >> 9) & 7, nt = idx >> 12;
        whhf_sw[idx] = (f16)whhf[(nt * 16 + c) * 256 + ks * 32 + q * 8 + j];
        return;
    }
    idx -= 262144;
    if (idx < 262144) {  // whhb_sw
        int j = idx & 7, lane = (idx >> 3) & 63, c = lane & 15, q = lane >> 4;
        int ks = (idx >> 9) & 7, nt = idx >> 12;
        whhb_sw[idx] = (f16)whhb[(nt * 16 + c) * 256 + ks * 32 + q * 8 + j];
        return;
    }
    idx -= 262144;
    if (idx < 1310720) { // decwih_sw: N=2048 x K=640
        int j = idx & 7, lane = (idx >> 3) & 63, c = lane & 15, q = lane >> 4;
        int r2 = idx >> 9; int ks = r2 % 20, nt = r2 / 20;
        decwih_sw[idx] = (f16)dec_wih[(nt * 16 + c) * 640 + ks * 32 + q * 8 + j];
        return;
    }
    idx -= 1310720;
    if (idx < 1048576) { // decwhh_sw: N=2048 x K=512
        int j = idx & 7, lane = (idx >> 3) & 63, c = lane & 15, q = lane >> 4;
        int ks = (idx >> 9) & 15, nt = idx >> 13;
        decwhh_sw[idx] = (f16)dec_whh[(nt * 16 + c) * 512 + ks * 32 + q * 8 + j];
        return;
    }
    idx -= 1048576;
    if (idx < 262144) { int e = idx >> 9, d = idx & 511; WeT[idx] = (f16)attn_W[(512 + d) * 512 + e]; return; }
    idx -= 262144;
    if (idx < 16384)  { emb16[idx] = (f16)enc_emb[idx]; return; }
    idx -= 16384;
    if (idx < 131072) { wihf16[idx] = (f16)wihf[idx]; return; }
    idx -= 131072;
    if (idx < 131072) { wihb16[idx] = (f16)wihb[idx]; return; }
    idx -= 131072;
    if (idx < 16384)  { decemb16[idx] = (f16)dec_emb[idx]; return; }
    idx -= 16384;
    if (idx < 16384)  { int b = idx >> 7, v = idx & 127; out[b * 16384 + v] = 0.f; return; }
}

// ---------------------------------------------------------------------------
// K_vocab: xg_vocab[v][n] = emb[v] @ [Wih_f|Wih_b]^T + [b_f|b_b] (once).
// ---------------------------------------------------------------------------
__global__ __launch_bounds__(256) void k_vocab(
    const f16* __restrict__ emb, const f16* __restrict__ wihf,
    const f16* __restrict__ wihb, const float* __restrict__ bf_,
    const float* __restrict__ bb_, f16* __restrict__ xg_vocab)
{
    int bn = blockIdx.x;
    int tid = threadIdx.x, wave = tid >> 6, lane = tid & 63;
    int col = lane & 15, quad = lane >> 4;
    int wr = wave >> 1, wc = wave & 1;

    f32x4 acc[4][4] = {};
    for (int ks = 0; ks < 4; ++ks) {
        int k0 = ks * 32 + quad * 8;
        half8 a[4], bfr[4];
        for (int i = 0; i < 4; ++i)
            a[i] = *(const half8*)(emb + (wr * 64 + i * 16 + col) * 128 + k0);
        for (int j = 0; j < 4; ++j) {
            int n = bn * 128 + wc * 64 + j * 16 + col;
            const f16* wp = (n < 1024) ? (wihf + n * 128) : (wihb + (n - 1024) * 128);
            bfr[j] = *(const half8*)(wp + k0);
        }
        for (int i = 0; i < 4; ++i)
            for (int j = 0; j < 4; ++j)
                acc[i][j] = MFMA16(a[i], bfr[j], acc[i][j]);
    }
    for (int j = 0; j < 4; ++j) {
        int n = bn * 128 + wc * 64 + j * 16 + col;
        float bias = (n < 1024) ? bf_[n] : bb_[n - 1024];
        for (int i = 0; i < 4; ++i) {
            int vbase = wr * 64 + i * 16 + quad * 4;
            for (int r = 0; r < 4; ++r)
                xg_vocab[(vbase + r) * 2048 + n] = (f16)(acc[i][j][r] + bias);
        }
    }
}

// ---------------------------------------------------------------------------
// K_enc: encoder scan, 16 persistent blocks (2 dir x 8 batch-groups of 16),
// 512 threads.  (unchanged -- known correct)
// ---------------------------------------------------------------------------
__global__ __launch_bounds__(512) void k_enc(
    const int* __restrict__ src, const f16* __restrict__ xg_vocab,
    const f16* __restrict__ whhf_sw, const f16* __restrict__ whhb_sw,
    f16* __restrict__ enc_out, f16* __restrict__ hdec0, float* __restrict__ c_ws)
{
    int blk = blockIdx.x;
    int dir = blk >> 3, bbase = (blk & 7) * 16;
    int tid = threadIdx.x, wave = tid >> 6, lane = tid & 63;
    int col = lane & 15, quad = lane >> 4;
    const f16* whh = dir ? whhb_sw : whhf_sw;

    __shared__ f16 hb[16][264];
    __shared__ f16 xvb[16][1032];
    __shared__ int stok[16];
    for (int z = tid; z < 16 * 264; z += 512) ((f16*)hb)[z] = (f16)0.f;
    float cc[2][4] = {};
    __syncthreads();

    for (int t = 0; t < 512; ++t) {
        int ts = dir ? (511 - t) : t;
        if (tid < 16) stok[tid] = src[(bbase + tid) * 512 + ts];
        half8 a[8];
        #pragma unroll
        for (int kk = 0; kk < 8; ++kk)
            a[kk] = *(const half8*)(&hb[col][kk * 32 + quad * 8]);
        __syncthreads();

        #pragma unroll
        for (int it = 0; it < 4; ++it) {
            int cnk = it * 512 + tid;
            int row = cnk >> 7, off = (cnk & 127) * 8;
            *(half8*)(&xvb[row][off]) =
                *(const half8*)(xg_vocab + stok[row] * 2048 + dir * 1024 + off);
        }

        f32x4 acc[4][2] = {};
        #pragma unroll
        for (int kk = 0; kk < 8; ++kk) {
            half8 bv[8];
            #pragma unroll
            for (int g = 0; g < 4; ++g)
                #pragma unroll
                for (int nt = 0; nt < 2; ++nt) {
                    int tile = g * 16 + wave * 2 + nt;
                    bv[g * 2 + nt] = *(const half8*)(whh + ((tile * 8 + kk) * 64 + lane) * 8);
                }
            #pragma unroll
            for (int g = 0; g < 4; ++g)
                #pragma unroll
                for (int nt = 0; nt < 2; ++nt)
                    acc[g][nt] = MFMA16(a[kk], bv[g * 2 + nt], acc[g][nt]);
        }
        __syncthreads();

        #pragma unroll
        for (int nt = 0; nt < 2; ++nt) {
            int hcol = wave * 32 + nt * 16 + col;
            #pragma unroll
            for (int r = 0; r < 4; ++r) {
                int b = quad * 4 + r;
                float gi = (float)xvb[b][0 * 256 + hcol] + acc[0][nt][r];
                float gf = (float)xvb[b][1 * 256 + hcol] + acc[1][nt][r];
                float gg = (float)xvb[b][2 * 256 + hcol] + acc[2][nt][r];
                float go = (float)xvb[b][3 * 256 + hcol] + acc[3][nt][r];
                float ig = fsig(gi), fg = fsig(gf), g2 = ftanh(gg), og = fsig(go);
                float cv = fg * cc[nt][r] + ig * g2;
                cc[nt][r] = cv;
                float h = og * ftanh(cv);
                f16 h16 = (f16)h;
                hb[b][hcol] = h16;
                enc_out[((size_t)(bbase + b) * 512 + ts) * 512 + dir * 256 + hcol] = h16;
            }
        }
        __syncthreads();
    }
    #pragma unroll
    for (int nt = 0; nt < 2; ++nt) {
        int hcol = wave * 32 + nt * 16 + col;
        #pragma unroll
        for (int r = 0; r < 4; ++r) {
            int b = quad * 4 + r;
            int m = bbase + b, k = dir * 256 + hcol;
            hdec0[frag_idx(m, k, 16)] = hb[b][hcol];
            c_ws[m * 512 + k] = cc[nt][r];
        }
    }
}

// ---------------------------------------------------------------------------
// K_proj: enc_proj = enc_out @ We (once).
// ---------------------------------------------------------------------------
__global__ __launch_bounds__(256) void k_proj(
    const f16* __restrict__ enc_out, const f16* __restrict__ WeT,
    f16* __restrict__ proj)
{
    int blk = blockIdx.x;
    int bm = blk & 511, bn = blk >> 9;
    int tid = threadIdx.x, wave = tid >> 6, lane = tid & 63;
    int col = lane & 15, quad = lane >> 4;
    int wr = wave >> 1, wc = wave & 1;

    f32x4 acc[4][4] = {};
    for (int ks = 0; ks < 16; ++ks) {
        int k0 = ks * 32 + quad * 8;
        half8 a[4], bfr[4];
        for (int i = 0; i < 4; ++i) {
            int m = bm * 128 + wr * 64 + i * 16 + col;
            a[i] = *(const half8*)(enc_out + (size_t)m * 512 + k0);
        }
        for (int j = 0; j < 4; ++j) {
            int n = bn * 128 + wc * 64 + j * 16 + col;
            bfr[j] = *(const half8*)(WeT + n * 512 + k0);
        }
        for (int i = 0; i < 4; ++i)
            for (int j = 0; j < 4; ++j)
                acc[i][j] = MFMA16(a[i], bfr[j], acc[i][j]);
    }
    for (int j = 0; j < 4; ++j) {
        int n = bn * 128 + wc * 64 + j * 16 + col;
        for (int i = 0; i < 4; ++i) {
            int mbase = bm * 128 + wr * 64 + i * 16 + quad * 4;
            for (int r = 0; r < 4; ++r)
                proj[(size_t)(mbase + r) * 512 + n] = (f16)acc[i][j][r];
        }
    }
}

// ---------------------------------------------------------------------------
// K_qinit: initial q-partials (once).
// ---------------------------------------------------------------------------
__global__ __launch_bounds__(256) void k_qinit(
    const f16* __restrict__ h0_sw, const f16* __restrict__ WhT_sw,
    float* __restrict__ qpart)
{
    int j = blockIdx.x;
    int tid = threadIdx.x, wave = tid >> 6, lane = tid & 63;
    int col = lane & 15, quad = lane >> 4;
    half8 a[2];
    #pragma unroll
    for (int i = 0; i < 2; ++i)
        a[i] = *(const half8*)(h0_sw + (((wave * 2 + i) * 16 + j) * 64 + lane) * 8);
    for (int nt = 0; nt < 32; ++nt) {
        half8 bfr = *(const half8*)(WhT_sw + ((nt * 16 + j) * 64 + lane) * 8);
        f32x4 q0 = {}, q1 = {};
        q0 = MFMA16(a[0], bfr, q0);
        q1 = MFMA16(a[1], bfr, q1);
        #pragma unroll
        for (int r = 0; r < 4; ++r) {
            qpart[(j * 128 + wave * 32 + quad * 4 + r) * 512 + nt * 16 + col] = q0[r];
            qpart[(j * 128 + wave * 32 + 16 + quad * 4 + r) * 512 + nt * 16 + col] = q1[r];
        }
    }
}

// ---------------------------------------------------------------------------
// K_att (per step): 256 blocks x 512 thr; block = (b, sh) over 256 s-rows.
// R8's two-pass shape: scores pass (8-deep) -> block-local softmax stats ->
// ctx pass (8-deep half8) -> write unnormalized partial (M, l, ctx[512]).
// No atomics/fences; kernel boundary publishes.  sh==0 writes emb rows.
// ---------------------------------------------------------------------------
__global__ __launch_bounds__(512) void k_att(
    const f16* __restrict__ proj, const f16* __restrict__ enc_out,
    const float* __restrict__ qpart, const float* __restrict__ attn_b,
    const float* __restrict__ attn_v, const int* __restrict__ trg,
    const f16* __restrict__ dec_emb, f16* __restrict__ x_sw,
    float* __restrict__ part_m, float* __restrict__ part_l,
    float* __restrict__ part_ctx, int t)
{
    int blk = blockIdx.x;
    int b = blk >> 1, sh = blk & 1;
    int tid = threadIdx.x, wave = tid >> 6, lane = tid & 63;
    __shared__ float q[512];
    __shared__ float sc[256];
    __shared__ float ctxred[8][512];
    __shared__ float wred[8], wred2[8];

    {
        float s = attn_b[tid];
        #pragma unroll
        for (int jj = 0; jj < 16; ++jj) s += qpart[(jj * 128 + b) * 512 + tid];
        q[tid] = s;
    }
    __syncthreads();

    float qreg[8], vreg[8];
    #pragma unroll
    for (int u = 0; u < 8; ++u) {
        int e = lane * 8 + u;
        qreg[u] = q[e];
        vreg[u] = attn_v[e];
    }
    int sbase = sh * 256;
    // scores: wave w handles local rows sl = z8*8 + w; 8-deep batching
    for (int ib = 0; ib < 4; ++ib) {
        half8 p[8];
        #pragma unroll
        for (int z = 0; z < 8; ++z) {
            int sl = (ib * 8 + z) * 8 + wave;
            p[z] = *(const half8*)(proj + ((size_t)b * 512 + sbase + sl) * 512 + lane * 8);
        }
        #pragma unroll
        for (int z = 0; z < 8; ++z) {
            int sl = (ib * 8 + z) * 8 + wave;
            float part = 0.f;
            #pragma unroll
            for (int u = 0; u < 8; ++u)
                part += vreg[u] * ftanh(qreg[u] + (float)p[z][u]);
            #pragma unroll
            for (int o = 32; o; o >>= 1) part += __shfl_xor(part, o);
            if (lane == 0) sc[sl] = part;
        }
    }
    __syncthreads();

    // block-local softmax stats over 256 rows
    float s0 = (tid < 256) ? sc[tid] : -__builtin_inff();
    float mv = s0;
    #pragma unroll
    for (int o = 32; o; o >>= 1) mv = fmaxf(mv, __shfl_xor(mv, o));
    if (lane == 0) wred[wave] = mv;
    __syncthreads();
    float M = wred[0];
    #pragma unroll
    for (int w = 1; w < 8; ++w) M = fmaxf(M, wred[w]);
    float e0 = (tid < 256) ? __expf(s0 - M) : 0.f;
    if (tid < 256) sc[tid] = e0;   // overwrite with unnormalized weight
    float sm = e0;
    #pragma unroll
    for (int o = 32; o; o >>= 1) sm += __shfl_xor(sm, o);
    if (lane == 0) wred2[wave] = sm;
    __syncthreads();
    float lb = wred2[0];
    #pragma unroll
    for (int w = 1; w < 8; ++w) lb += wred2[w];

    // ctx: wave owns same 32 local rows; 8-deep half8 batching
    float a8[8] = {};
    for (int ib = 0; ib < 4; ++ib) {
        half8 ev[8];
        float wgt[8];
        #pragma unroll
        for (int z = 0; z < 8; ++z) {
            int sl = (ib * 8 + z) * 8 + wave;
            ev[z] = *(const half8*)(enc_out + ((size_t)b * 512 + sbase + sl) * 512 + lane * 8);
            wgt[z] = sc[sl];
        }
        #pragma unroll
        for (int z = 0; z < 8; ++z)
            #pragma unroll
            for (int u = 0; u < 8; ++u) a8[u] += wgt[z] * (float)ev[z][u];
    }
    #pragma unroll
    for (int u = 0; u < 8; ++u) ctxred[wave][lane * 8 + u] = a8[u];
    __syncthreads();
    float cp = 0.f;
    #pragma unroll
    for (int w = 0; w < 8; ++w) cp += ctxred[w][tid];
    part_ctx[(size_t)blk * 512 + tid] = cp;
    if (tid == 0) { part_m[blk] = M; part_l[blk] = lb; }

    if (sh == 0 && tid < 128) {
        int tok = trg[b * 128 + t];
        x_sw[frag_idx(b, tid, 20)] = dec_emb[tok * 128 + tid];
    }
}

// ---------------------------------------------------------------------------
// K_gates (per step): 32 blocks = (j n-slice, mh m-half).  Prologue combines
// the two softmax partials for THIS block's 64 batch rows into x_sw (same-mh
// blocks write identical values -- benign; each reads only its own writes).
// Then the proven R8 GEMM + in-lane LSTM + fused q-partial GEMM.
// ---------------------------------------------------------------------------
__global__ __launch_bounds__(256) void k_gates(
    f16* __restrict__ x_sw, const f16* __restrict__ hprev_sw,
    const f16* __restrict__ wih_sw, const f16* __restrict__ whh_sw,
    const float* __restrict__ dec_b, float* __restrict__ c_ws,
    f16* __restrict__ hnext_sw, f16* __restrict__ hhist_sw,
    const f16* __restrict__ WhT_sw, float* __restrict__ qpart,
    const float* __restrict__ part_m, const float* __restrict__ part_l,
    const float* __restrict__ part_ctx, int t)
{
    int jb = blockIdx.x;
    int j = jb >> 1, mh = jb & 1;
    int tid = threadIdx.x, wave = tid >> 6, lane = tid & 63;
    int col = lane & 15, quad = lane >> 4;
    __shared__ f16 hsl[64][40];
    __shared__ float gm[64][2];

    // ---- prologue: combine softmax partials for this block's 64 rows ----
    if (tid < 64) {
        int bb = mh * 64 + tid;
        float m0 = part_m[bb * 2 + 0], m1 = part_m[bb * 2 + 1];
        float l0 = part_l[bb * 2 + 0], l1 = part_l[bb * 2 + 1];
        float M = fmaxf(m0, m1);
        float g0 = __expf(m0 - M), g1 = __expf(m1 - M);
        float inv = 1.f / (g0 * l0 + g1 * l1);
        gm[tid][0] = g0 * inv;
        gm[tid][1] = g1 * inv;
    }
    __syncthreads();
    for (int z = tid; z < 32768; z += 256) {
        int lr = z >> 9, d = z & 511;
        int bb = mh * 64 + lr;
        float c = gm[lr][0] * part_ctx[(size_t)(bb * 2 + 0) * 512 + d]
                + gm[lr][1] * part_ctx[(size_t)(bb * 2 + 1) * 512 + d];
        x_sw[frag_idx(bb, 128 + d, 20)] = (f16)c;
    }
    __syncthreads();

    // ---- GEMM: gates = [x|h] @ [Wih|Whh]^T ----
    f32x4 acc[8] = {};
    for (int ks = 0; ks < 36; ++ks) {
        int mtile = mh * 4 + wave;
        half8 a = (ks < 20)
            ? *(const half8*)(x_sw + ((mtile * 20 + ks) * 64 + lane) * 8)
            : *(const half8*)(hprev_sw + ((mtile * 16 + (ks - 20)) * 64 + lane) * 8);
        half8 bv[8];
        #pragma unroll
        for (int jt = 0; jt < 8; ++jt) {
            int g = jt >> 1, u2 = jt & 1;
            int ntile = g * 32 + j * 2 + u2;
            bv[jt] = (ks < 20)
                ? *(const half8*)(wih_sw + ((ntile * 20 + ks) * 64 + lane) * 8)
                : *(const half8*)(whh_sw + ((ntile * 16 + (ks - 20)) * 64 + lane) * 8);
        }
        #pragma unroll
        for (int jt = 0; jt < 8; ++jt)
            acc[jt] = MFMA16(a, bv[jt], acc[jt]);
    }
    float bias[8];
    #pragma unroll
    for (int jt = 0; jt < 8; ++jt) {
        int g = jt >> 1, u2 = jt & 1;
        bias[jt] = dec_b[g * 512 + j * 32 + u2 * 16 + col];
    }
    #pragma unroll
    for (int r = 0; r < 4; ++r) {
        int lb = wave * 16 + quad * 4 + r;
        int bb = mh * 64 + lb;
        #pragma unroll
        for (int u2 = 0; u2 < 2; ++u2) {
            int hl = u2 * 16 + col, hcol = j * 32 + hl;
            float gi = acc[0 + u2][r] + bias[0 + u2];
            float gf = acc[2 + u2][r] + bias[2 + u2];
            float gg = acc[4 + u2][r] + bias[4 + u2];
            float go = acc[6 + u2][r] + bias[6 + u2];
            float ig = fsig(gi), fg = fsig(gf), g2 = ftanh(gg), og = fsig(go);
            float cv = fg * c_ws[bb * 512 + hcol] + ig * g2;
            c_ws[bb * 512 + hcol] = cv;
            float h = og * ftanh(cv);
            f16 h16 = (f16)h;
            int fidx = frag_idx(bb, hcol, 16);
            hnext_sw[fidx] = h16;
            hhist_sw[t * 65536 + fidx] = h16;
            hsl[lb][hl] = h16;
        }
    }
    // fused q-partials for next step (wave reads its own hsl rows)
    half8 aq = *(const half8*)(&hsl[wave * 16 + col][quad * 8]);
    for (int nt = 0; nt < 32; ++nt) {
        half8 bq = *(const half8*)(WhT_sw + ((nt * 16 + j) * 64 + lane) * 8);
        f32x4 q0 = {};
        q0 = MFMA16(aq, bq, q0);
        #pragma unroll
        for (int r = 0; r < 4; ++r)
            qpart[(j * 128 + mh * 64 + wave * 16 + quad * 4 + r) * 512 + nt * 16 + col] = q0[r];
    }
}

// ---------------------------------------------------------------------------
// K_logits: batched over all 127 steps (once).
// ---------------------------------------------------------------------------
__global__ __launch_bounds__(256) void k_logits(
    const f16* __restrict__ hhist_sw, const f16* __restrict__ outWT_sw,
    const float* __restrict__ out_b, float* __restrict__ out)
{
    int bt = blockIdx.x;
    int tid = threadIdx.x, wave = tid >> 6, lane = tid & 63;
    int col = lane & 15, quad = lane >> 4;
    f32x4 acc[2][8] = {};
    for (int ks = 0; ks < 16; ++ks) {
        half8 a[2];
        #pragma unroll
        for (int i = 0; i < 2; ++i)
            a[i] = *(const half8*)(hhist_sw + bt * 65536 + (((wave * 2 + i) * 16 + ks) * 64 + lane) * 8);
        half8 bv[8];
        #pragma unroll
        for (int jt = 0; jt < 8; ++jt)
            bv[jt] = *(const half8*)(outWT_sw + ((jt * 16 + ks) * 64 + lane) * 8);
        #pragma unroll
        for (int jt = 0; jt < 8; ++jt) {
            acc[0][jt] = MFMA16(a[0], bv[jt], acc[0][jt]);
            acc[1][jt] = MFMA16(a[1], bv[jt], acc[1][jt]);
        }
    }
    #pragma unroll
    for (int jt = 0; jt < 8; ++jt) {
        float bias = out_b[jt * 16 + col];
        #pragma unroll
        for (int i = 0; i < 2; ++i)
            #pragma unroll
            for (int r = 0; r < 4; ++r) {
                int br = wave * 32 + i * 16 + quad * 4 + r;
                out[br * 16384 + (bt + 1) * 128 + jt * 16 + col] = acc[i][jt][r] + bias;
            }
    }
}

// ---------------------------------------------------------------------------
extern "C" void kernel_launch(void* const* d_in, const int* in_sizes, int n_in,
                              void* d_out, int out_size, void* d_ws, size_t ws_size,
                              hipStream_t stream)
{
    (void)in_sizes; (void)n_in; (void)out_size;
    if (ws_size < 164000000) return;  // clean bail if workspace too small

    const int*   src     = (const int*)d_in[0];
    const int*   trg     = (const int*)d_in[1];
    const float* enc_emb = (const float*)d_in[2];
    const float* wihf    = (const float*)d_in[3];
    const float* whhf    = (const float*)d_in[4];
    const float* bf_     = (const float*)d_in[5];
    const float* wihb    = (const float*)d_in[6];
    const float* whhb    = (const float*)d_in[7];
    const float* bb_     = (const float*)d_in[8];
    const float* dec_emb = (const float*)d_in[9];
    const float* dec_wih = (const float*)d_in[10];
    const float* dec_whh = (const float*)d_in[11];
    const float* dec_b   = (const float*)d_in[12];
    const float* attn_W  = (const float*)d_in[13];
    const float* attn_b  = (const float*)d_in[14];
    const float* attn_v  = (const float*)d_in[15];
    const float* out_W   = (const float*)d_in[16];
    const float* out_b   = (const float*)d_in[17];
    float* out = (float*)d_out;

    char* p = (char*)d_ws;
    auto carve = [&](size_t n) { char* r = p; p += ((n + 255) & ~(size_t)255); return r; };
    f16*   enc_out   = (f16*)  carve(67108864);
    f16*   proj      = (f16*)  carve(67108864);
    f16*   WhT_sw    = (f16*)  carve(524288);
    f16*   WeT       = (f16*)  carve(524288);
    f16*   outWT_sw  = (f16*)  carve(131072);
    f16*   emb16     = (f16*)  carve(32768);
    f16*   wihf16    = (f16*)  carve(262144);
    f16*   wihb16    = (f16*)  carve(262144);
    f16*   whhf_sw   = (f16*)  carve(524288);
    f16*   whhb_sw   = (f16*)  carve(524288);
    f16*   decemb16  = (f16*)  carve(32768);
    f16*   decwih_sw = (f16*)  carve(2621440);
    f16*   decwhh_sw = (f16*)  carve(2097152);
    float* qpart     = (float*)carve(4194304);
    f16*   hdec0     = (f16*)  carve(131072);
    f16*   hdec1     = (f16*)  carve(131072);
    float* c_ws      = (float*)carve(262144);
    f16*   x_sw      = (f16*)  carve(163840);
    f16*   hhist_sw  = (f16*)  carve(16646144);
    f16*   xg_vocab  = (f16*)  carve(524288);
    float* part_m    = (float*)carve(2048);
    float* part_l    = (float*)carve(2048);
    float* part_ctx  = (float*)carve(524288);

    k_prep<<<14784, 256, 0, stream>>>(attn_W, out_W, enc_emb, wihf, wihb, whhf, whhb,
                                      dec_emb, dec_wih, dec_whh,
                                      WhT_sw, outWT_sw, whhf_sw, whhb_sw,
                                      decwih_sw, decwhh_sw, WeT, emb16,
                                      wihf16, wihb16, decemb16, out);
    k_vocab<<<16, 256, 0, stream>>>(emb16, wihf16, wihb16, bf_, bb_, xg_vocab);
    k_enc<<<16, 512, 0, stream>>>(src, xg_vocab, whhf_sw, whhb_sw, enc_out, hdec0, c_ws);
    k_proj<<<2048, 256, 0, stream>>>(enc_out, WeT, proj);
    k_qinit<<<16, 256, 0, stream>>>(hdec0, WhT_sw, qpart);
    for (int t = 0; t < 127; ++t) {
        k_att<<<256, 512, 0, stream>>>(proj, enc_out, qpart, attn_b, attn_v,
                                       trg, decemb16, x_sw, part_m, part_l,
                                       part_ctx, t);
        f16* hin  = (t & 1) ? hdec1 : hdec0;
        f16* hout = (t & 1) ? hdec0 : hdec1;
        k_gates<<<32, 256, 0, stream>>>(x_sw, hin, decwih_sw, decwhh_sw, dec_b,
                                        c_ws, hout, hhist_sw, WhT_sw, qpart,
                                        part_m, part_l, part_ctx, t);
    }
    k_logits<<<127, 256, 0, stream>>>(hhist_sw, outWT_sw, out_b, out);
}

// Round 10
// 13304.655 us; speedup vs baseline: 3.8259x; 1.0221x over previous
//
#include <hip/hip_runtime.h>

// ============================================================================
// Seq2Seq (bi-LSTM encoder + Bahdanau-attention LSTM decoder) on gfx950.
// fp32 in/out; fp16 internal (fp32 accum/state).
// R10 = R9 (13.60 ms) + k_enc register-resident half-Whh:
//   each wave keeps its gate-0/1 B-fragments (128 VGPRs) live across all 512
//   steps; only gates 2/3 stream from L2.  Halves the per-step Whh stream
//   (512->256 KB/block) -- k_enc's floor is per-CU L2 BW.
// ============================================================================

typedef _Float16 f16;
typedef _Float16 half8 __attribute__((ext_vector_type(8)));
typedef float f32x4 __attribute__((ext_vector_type(4)));

#define MFMA16(a, b, c) __builtin_amdgcn_mfma_f32_16x16x32_f16((a), (b), (c), 0, 0, 0)

__device__ __forceinline__ float fsig(float x) {
    return __builtin_amdgcn_rcpf(1.f + __expf(-x));
}
__device__ __forceinline__ float ftanh(float x) {
    return 1.f - 2.f * __builtin_amdgcn_rcpf(1.f + __expf(2.f * x));
}
__device__ __forceinline__ int frag_idx(int m, int k, int KS) {
    return (((m >> 4) * KS + (k >> 5)) * 64 + (((k >> 3) & 3) * 16 + (m & 15))) * 8 + (k & 7);
}

// ---------------------------------------------------------------------------
// K0: one-shot: pack weights to fragment order (f32 -> f16), plain converts,
// zero out t=0 output row.
// ---------------------------------------------------------------------------
__global__ __launch_bounds__(256) void k_prep(
    const float* __restrict__ attn_W, const float* __restrict__ out_W,
    const float* __restrict__ enc_emb,
    const float* __restrict__ wihf, const float* __restrict__ wihb,
    const float* __restrict__ whhf, const float* __restrict__ whhb,
    const float* __restrict__ dec_emb, const float* __restrict__ dec_wih,
    const float* __restrict__ dec_whh,
    f16* __restrict__ WhT_sw, f16* __restrict__ outWT_sw,
    f16* __restrict__ whhf_sw, f16* __restrict__ whhb_sw,
    f16* __restrict__ decwih_sw, f16* __restrict__ decwhh_sw,
    f16* __restrict__ WeT, f16* __restrict__ emb16,
    f16* __restrict__ wihf16, f16* __restrict__ wihb16,
    f16* __restrict__ decemb16, float* __restrict__ out)
{
    long i = (long)blockIdx.x * 256 + threadIdx.x;
    if (i >= 3784704L) return;
    long idx = i;
    if (idx < 262144) {  // WhT_sw: N=512(e) x K=512(d)
        int j = idx & 7, lane = (idx >> 3) & 63, c = lane & 15, q = lane >> 4;
        int ks = (idx >> 9) & 15, nt = idx >> 13;
        WhT_sw[idx] = (f16)attn_W[(ks * 32 + q * 8 + j) * 512 + nt * 16 + c];
        return;
    }
    idx -= 262144;
    if (idx < 65536) {   // outWT_sw: N=128(v) x K=512(d)
        int j = idx & 7, lane = (idx >> 3) & 63, c = lane & 15, q = lane >> 4;
        int ks = (idx >> 9) & 15, nt = idx >> 13;
        outWT_sw[idx] = (f16)out_W[(ks * 32 + q * 8 + j) * 128 + nt * 16 + c];
        return;
    }
    idx -= 65536;
    if (idx < 262144) {  // whhf_sw: N=1024 x K=256
        int j = idx & 7, lane = (idx >> 3) & 63, c = lane & 15, q = lane >> 4;
        int ks = (idx >> 9) & 7, nt = idx >> 12;
        whhf_sw[idx] = (f16)whhf[(nt * 16 + c) * 256 + ks * 32 + q * 8 + j];
        return;
    }
    idx -= 262144;
    if (idx < 262144) {  // whhb_sw
        int j = idx & 7, lane = (idx >> 3) & 63, c = lane & 15, q = lane >> 4;
        int ks = (idx >> 9) & 7, nt = idx >> 12;
        whhb_sw[idx] = (f16)whhb[(nt * 16 + c) * 256 + ks * 32 + q * 8 + j];
        return;
    }
    idx -= 262144;
    if (idx < 1310720) { // decwih_sw: N=2048 x K=640
        int j = idx & 7, lane = (idx >> 3) & 63, c = lane & 15, q = lane >> 4;
        int r2 = idx >> 9; int ks = r2 % 20, nt = r2 / 20;
        decwih_sw[idx] = (f16)dec_wih[(nt * 16 + c) * 640 + ks * 32 + q * 8 + j];
        return;
    }
    idx -= 1310720;
    if (idx < 1048576) { // decwhh_sw: N=2048 x K=512
        int j = idx & 7, lane = (idx >> 3) & 63, c = lane & 15, q = lane >> 4;
        int ks = (idx >> 9) & 15, nt = idx >> 13;
        decwhh_sw[idx] = (f16)dec_whh[(nt * 16 + c) * 512 + ks * 32 + q * 8 + j];
        return;
    }
    idx -= 1048576;
    if (idx < 262144) { int e = idx >> 9, d = idx & 511; WeT[idx] = (f16)attn_W[(512 + d) * 512 + e]; return; }
    idx -= 262144;
    if (idx < 16384)  { emb16[idx] = (f16)enc_emb[idx]; return; }
    idx -= 16384;
    if (idx < 131072) { wihf16[idx] = (f16)wihf[idx]; return; }
    idx -= 131072;
    if (idx < 131072) { wihb16[idx] = (f16)wihb[idx]; return; }
    idx -= 131072;
    if (idx < 16384)  { decemb16[idx] = (f16)dec_emb[idx]; return; }
    idx -= 16384;
    if (idx < 16384)  { int b = idx >> 7, v = idx & 127; out[b * 16384 + v] = 0.f; return; }
}

// ---------------------------------------------------------------------------
// K_vocab: xg_vocab[v][n] = emb[v] @ [Wih_f|Wih_b]^T + [b_f|b_b] (once).
// ---------------------------------------------------------------------------
__global__ __launch_bounds__(256) void k_vocab(
    const f16* __restrict__ emb, const f16* __restrict__ wihf,
    const f16* __restrict__ wihb, const float* __restrict__ bf_,
    const float* __restrict__ bb_, f16* __restrict__ xg_vocab)
{
    int bn = blockIdx.x;
    int tid = threadIdx.x, wave = tid >> 6, lane = tid & 63;
    int col = lane & 15, quad = lane >> 4;
    int wr = wave >> 1, wc = wave & 1;

    f32x4 acc[4][4] = {};
    for (int ks = 0; ks < 4; ++ks) {
        int k0 = ks * 32 + quad * 8;
        half8 a[4], bfr[4];
        for (int i = 0; i < 4; ++i)
            a[i] = *(const half8*)(emb + (wr * 64 + i * 16 + col) * 128 + k0);
        for (int j = 0; j < 4; ++j) {
            int n = bn * 128 + wc * 64 + j * 16 + col;
            const f16* wp = (n < 1024) ? (wihf + n * 128) : (wihb + (n - 1024) * 128);
            bfr[j] = *(const half8*)(wp + k0);
        }
        for (int i = 0; i < 4; ++i)
            for (int j = 0; j < 4; ++j)
                acc[i][j] = MFMA16(a[i], bfr[j], acc[i][j]);
    }
    for (int j = 0; j < 4; ++j) {
        int n = bn * 128 + wc * 64 + j * 16 + col;
        float bias = (n < 1024) ? bf_[n] : bb_[n - 1024];
        for (int i = 0; i < 4; ++i) {
            int vbase = wr * 64 + i * 16 + quad * 4;
            for (int r = 0; r < 4; ++r)
                xg_vocab[(vbase + r) * 2048 + n] = (f16)(acc[i][j][r] + bias);
        }
    }
}

// ---------------------------------------------------------------------------
// K_enc: encoder scan, 16 persistent blocks (2 dir x 8 batch-groups of 16),
// 512 threads.  R10: gate-0/1 Whh fragments live in VGPRs across the whole
// 512-step loop (bst[32], fully unrolled); gates 2/3 stream from L2.
// ---------------------------------------------------------------------------
__global__ __launch_bounds__(512, 2) void k_enc(
    const int* __restrict__ src, const f16* __restrict__ xg_vocab,
    const f16* __restrict__ whhf_sw, const f16* __restrict__ whhb_sw,
    f16* __restrict__ enc_out, f16* __restrict__ hdec0, float* __restrict__ c_ws)
{
    int blk = blockIdx.x;
    int dir = blk >> 3, bbase = (blk & 7) * 16;
    int tid = threadIdx.x, wave = tid >> 6, lane = tid & 63;
    int col = lane & 15, quad = lane >> 4;
    const f16* whh = dir ? whhb_sw : whhf_sw;

    __shared__ f16 hb[16][264];
    __shared__ f16 xvb[16][1032];
    __shared__ int stok[16];
    for (int z = tid; z < 16 * 264; z += 512) ((f16*)hb)[z] = (f16)0.f;
    float cc[2][4] = {};

    // Register-resident B-fragments for gates 0,1 (32 x 1KB wave-loads).
    half8 bst[32];
    #pragma unroll
    for (int g = 0; g < 2; ++g)
        #pragma unroll
        for (int nt = 0; nt < 2; ++nt)
            #pragma unroll
            for (int kk = 0; kk < 8; ++kk) {
                int tile = g * 16 + wave * 2 + nt;
                bst[(g * 2 + nt) * 8 + kk] =
                    *(const half8*)(whh + ((tile * 8 + kk) * 64 + lane) * 8);
            }
    __syncthreads();

    for (int t = 0; t < 512; ++t) {
        int ts = dir ? (511 - t) : t;
        if (tid < 16) stok[tid] = src[(bbase + tid) * 512 + ts];
        half8 a[8];
        #pragma unroll
        for (int kk = 0; kk < 8; ++kk)
            a[kk] = *(const half8*)(&hb[col][kk * 32 + quad * 8]);
        __syncthreads();

        #pragma unroll
        for (int it = 0; it < 4; ++it) {
            int cnk = it * 512 + tid;
            int row = cnk >> 7, off = (cnk & 127) * 8;
            *(half8*)(&xvb[row][off]) =
                *(const half8*)(xg_vocab + stok[row] * 2048 + dir * 1024 + off);
        }

        f32x4 acc[4][2] = {};
        #pragma unroll
        for (int kk = 0; kk < 8; ++kk) {
            // streamed loads for gates 2,3
            half8 bv[4];
            #pragma unroll
            for (int g = 2; g < 4; ++g)
                #pragma unroll
                for (int nt = 0; nt < 2; ++nt) {
                    int tile = g * 16 + wave * 2 + nt;
                    bv[(g - 2) * 2 + nt] =
                        *(const half8*)(whh + ((tile * 8 + kk) * 64 + lane) * 8);
                }
            // static MFMAs (gates 0,1) cover the load latency
            #pragma unroll
            for (int g = 0; g < 2; ++g)
                #pragma unroll
                for (int nt = 0; nt < 2; ++nt)
                    acc[g][nt] = MFMA16(a[kk], bst[(g * 2 + nt) * 8 + kk], acc[g][nt]);
            // streamed MFMAs (gates 2,3)
            #pragma unroll
            for (int g = 2; g < 4; ++g)
                #pragma unroll
                for (int nt = 0; nt < 2; ++nt)
                    acc[g][nt] = MFMA16(a[kk], bv[(g - 2) * 2 + nt], acc[g][nt]);
        }
        __syncthreads();

        #pragma unroll
        for (int nt = 0; nt < 2; ++nt) {
            int hcol = wave * 32 + nt * 16 + col;
            #pragma unroll
            for (int r = 0; r < 4; ++r) {
                int b = quad * 4 + r;
                float gi = (float)xvb[b][0 * 256 + hcol] + acc[0][nt][r];
                float gf = (float)xvb[b][1 * 256 + hcol] + acc[1][nt][r];
                float gg = (float)xvb[b][2 * 256 + hcol] + acc[2][nt][r];
                float go = (float)xvb[b][3 * 256 + hcol] + acc[3][nt][r];
                float ig = fsig(gi), fg = fsig(gf), g2 = ftanh(gg), og = fsig(go);
                float cv = fg * cc[nt][r] + ig * g2;
                cc[nt][r] = cv;
                float h = og * ftanh(cv);
                f16 h16 = (f16)h;
                hb[b][hcol] = h16;
                enc_out[((size_t)(bbase + b) * 512 + ts) * 512 + dir * 256 + hcol] = h16;
            }
        }
        __syncthreads();
    }
    #pragma unroll
    for (int nt = 0; nt < 2; ++nt) {
        int hcol = wave * 32 + nt * 16 + col;
        #pragma unroll
        for (int r = 0; r < 4; ++r) {
            int b = quad * 4 + r;
            int m = bbase + b, k = dir * 256 + hcol;
            hdec0[frag_idx(m, k, 16)] = hb[b][hcol];
            c_ws[m * 512 + k] = cc[nt][r];
        }
    }
}

// ---------------------------------------------------------------------------
// K_proj: enc_proj = enc_out @ We (once).
// ---------------------------------------------------------------------------
__global__ __launch_bounds__(256) void k_proj(
    const f16* __restrict__ enc_out, const f16* __restrict__ WeT,
    f16* __restrict__ proj)
{
    int blk = blockIdx.x;
    int bm = blk & 511, bn = blk >> 9;
    int tid = threadIdx.x, wave = tid >> 6, lane = tid & 63;
    int col = lane & 15, quad = lane >> 4;
    int wr = wave >> 1, wc = wave & 1;

    f32x4 acc[4][4] = {};
    for (int ks = 0; ks < 16; ++ks) {
        int k0 = ks * 32 + quad * 8;
        half8 a[4], bfr[4];
        for (int i = 0; i < 4; ++i) {
            int m = bm * 128 + wr * 64 + i * 16 + col;
            a[i] = *(const half8*)(enc_out + (size_t)m * 512 + k0);
        }
        for (int j = 0; j < 4; ++j) {
            int n = bn * 128 + wc * 64 + j * 16 + col;
            bfr[j] = *(const half8*)(WeT + n * 512 + k0);
        }
        for (int i = 0; i < 4; ++i)
            for (int j = 0; j < 4; ++j)
                acc[i][j] = MFMA16(a[i], bfr[j], acc[i][j]);
    }
    for (int j = 0; j < 4; ++j) {
        int n = bn * 128 + wc * 64 + j * 16 + col;
        for (int i = 0; i < 4; ++i) {
            int mbase = bm * 128 + wr * 64 + i * 16 + quad * 4;
            for (int r = 0; r < 4; ++r)
                proj[(size_t)(mbase + r) * 512 + n] = (f16)acc[i][j][r];
        }
    }
}

// ---------------------------------------------------------------------------
// K_qinit: initial q-partials (once).
// ---------------------------------------------------------------------------
__global__ __launch_bounds__(256) void k_qinit(
    const f16* __restrict__ h0_sw, const f16* __restrict__ WhT_sw,
    float* __restrict__ qpart)
{
    int j = blockIdx.x;
    int tid = threadIdx.x, wave = tid >> 6, lane = tid & 63;
    int col = lane & 15, quad = lane >> 4;
    half8 a[2];
    #pragma unroll
    for (int i = 0; i < 2; ++i)
        a[i] = *(const half8*)(h0_sw + (((wave * 2 + i) * 16 + j) * 64 + lane) * 8);
    for (int nt = 0; nt < 32; ++nt) {
        half8 bfr = *(const half8*)(WhT_sw + ((nt * 16 + j) * 64 + lane) * 8);
        f32x4 q0 = {}, q1 = {};
        q0 = MFMA16(a[0], bfr, q0);
        q1 = MFMA16(a[1], bfr, q1);
        #pragma unroll
        for (int r = 0; r < 4; ++r) {
            qpart[(j * 128 + wave * 32 + quad * 4 + r) * 512 + nt * 16 + col] = q0[r];
            qpart[(j * 128 + wave * 32 + 16 + quad * 4 + r) * 512 + nt * 16 + col] = q1[r];
        }
    }
}

// ---------------------------------------------------------------------------
// K_att (per step): 256 blocks x 512 thr; block = (b, sh) over 256 s-rows.
// Two-pass shape: scores pass (8-deep) -> block-local softmax stats ->
// ctx pass (8-deep half8) -> write unnormalized partial (M, l, ctx[512]).
// ---------------------------------------------------------------------------
__global__ __launch_bounds__(512) void k_att(
    const f16* __restrict__ proj, const f16* __restrict__ enc_out,
    const float* __restrict__ qpart, const float* __restrict__ attn_b,
    const float* __restrict__ attn_v, const int* __restrict__ trg,
    const f16* __restrict__ dec_emb, f16* __restrict__ x_sw,
    float* __restrict__ part_m, float* __restrict__ part_l,
    float* __restrict__ part_ctx, int t)
{
    int blk = blockIdx.x;
    int b = blk >> 1, sh = blk & 1;
    int tid = threadIdx.x, wave = tid >> 6, lane = tid & 63;
    __shared__ float q[512];
    __shared__ float sc[256];
    __shared__ float ctxred[8][512];
    __shared__ float wred[8], wred2[8];

    {
        float s = attn_b[tid];
        #pragma unroll
        for (int jj = 0; jj < 16; ++jj) s += qpart[(jj * 128 + b) * 512 + tid];
        q[tid] = s;
    }
    __syncthreads();

    float qreg[8], vreg[8];
    #pragma unroll
    for (int u = 0; u < 8; ++u) {
        int e = lane * 8 + u;
        qreg[u] = q[e];
        vreg[u] = attn_v[e];
    }
    int sbase = sh * 256;
    // scores: wave w handles local rows sl = z8*8 + w; 8-deep batching
    for (int ib = 0; ib < 4; ++ib) {
        half8 p[8];
        #pragma unroll
        for (int z = 0; z < 8; ++z) {
            int sl = (ib * 8 + z) * 8 + wave;
            p[z] = *(const half8*)(proj + ((size_t)b * 512 + sbase + sl) * 512 + lane * 8);
        }
        #pragma unroll
        for (int z = 0; z < 8; ++z) {
            int sl = (ib * 8 + z) * 8 + wave;
            float part = 0.f;
            #pragma unroll
            for (int u = 0; u < 8; ++u)
                part += vreg[u] * ftanh(qreg[u] + (float)p[z][u]);
            #pragma unroll
            for (int o = 32; o; o >>= 1) part += __shfl_xor(part, o);
            if (lane == 0) sc[sl] = part;
        }
    }
    __syncthreads();

    // block-local softmax stats over 256 rows
    float s0 = (tid < 256) ? sc[tid] : -__builtin_inff();
    float mv = s0;
    #pragma unroll
    for (int o = 32; o; o >>= 1) mv = fmaxf(mv, __shfl_xor(mv, o));
    if (lane == 0) wred[wave] = mv;
    __syncthreads();
    float M = wred[0];
    #pragma unroll
    for (int w = 1; w < 8; ++w) M = fmaxf(M, wred[w]);
    float e0 = (tid < 256) ? __expf(s0 - M) : 0.f;
    if (tid < 256) sc[tid] = e0;   // overwrite with unnormalized weight
    float sm = e0;
    #pragma unroll
    for (int o = 32; o; o >>= 1) sm += __shfl_xor(sm, o);
    if (lane == 0) wred2[wave] = sm;
    __syncthreads();
    float lb = wred2[0];
    #pragma unroll
    for (int w = 1; w < 8; ++w) lb += wred2[w];

    // ctx: wave owns same 32 local rows; 8-deep half8 batching
    float a8[8] = {};
    for (int ib = 0; ib < 4; ++ib) {
        half8 ev[8];
        float wgt[8];
        #pragma unroll
        for (int z = 0; z < 8; ++z) {
            int sl = (ib * 8 + z) * 8 + wave;
            ev[z] = *(const half8*)(enc_out + ((size_t)b * 512 + sbase + sl) * 512 + lane * 8);
            wgt[z] = sc[sl];
        }
        #pragma unroll
        for (int z = 0; z < 8; ++z)
            #pragma unroll
            for (int u = 0; u < 8; ++u) a8[u] += wgt[z] * (float)ev[z][u];
    }
    #pragma unroll
    for (int u = 0; u < 8; ++u) ctxred[wave][lane * 8 + u] = a8[u];
    __syncthreads();
    float cp = 0.f;
    #pragma unroll
    for (int w = 0; w < 8; ++w) cp += ctxred[w][tid];
    part_ctx[(size_t)blk * 512 + tid] = cp;
    if (tid == 0) { part_m[blk] = M; part_l[blk] = lb; }

    if (sh == 0 && tid < 128) {
        int tok = trg[b * 128 + t];
        x_sw[frag_idx(b, tid, 20)] = dec_emb[tok * 128 + tid];
    }
}

// ---------------------------------------------------------------------------
// K_gates (per step): 32 blocks = (j n-slice, mh m-half).  Prologue combines
// the two softmax partials for THIS block's 64 batch rows into x_sw.
// Then the proven GEMM + in-lane LSTM + fused q-partial GEMM.
// ---------------------------------------------------------------------------
__global__ __launch_bounds__(256) void k_gates(
    f16* __restrict__ x_sw, const f16* __restrict__ hprev_sw,
    const f16* __restrict__ wih_sw, const f16* __restrict__ whh_sw,
    const float* __restrict__ dec_b, float* __restrict__ c_ws,
    f16* __restrict__ hnext_sw, f16* __restrict__ hhist_sw,
    const f16* __restrict__ WhT_sw, float* __restrict__ qpart,
    const float* __restrict__ part_m, const float* __restrict__ part_l,
    const float* __restrict__ part_ctx, int t)
{
    int jb = blockIdx.x;
    int j = jb >> 1, mh = jb & 1;
    int tid = threadIdx.x, wave = tid >> 6, lane = tid & 63;
    int col = lane & 15, quad = lane >> 4;
    __shared__ f16 hsl[64][40];
    __shared__ float gm[64][2];

    // ---- prologue: combine softmax partials for this block's 64 rows ----
    if (tid < 64) {
        int bb = mh * 64 + tid;
        float m0 = part_m[bb * 2 + 0], m1 = part_m[bb * 2 + 1];
        float l0 = part_l[bb * 2 + 0], l1 = part_l[bb * 2 + 1];
        float M = fmaxf(m0, m1);
        float g0 = __expf(m0 - M), g1 = __expf(m1 - M);
        float inv = 1.f / (g0 * l0 + g1 * l1);
        gm[tid][0] = g0 * inv;
        gm[tid][1] = g1 * inv;
    }
    __syncthreads();
    for (int z = tid; z < 32768; z += 256) {
        int lr = z >> 9, d = z & 511;
        int bb = mh * 64 + lr;
        float c = gm[lr][0] * part_ctx[(size_t)(bb * 2 + 0) * 512 + d]
                + gm[lr][1] * part_ctx[(size_t)(bb * 2 + 1) * 512 + d];
        x_sw[frag_idx(bb, 128 + d, 20)] = (f16)c;
    }
    __syncthreads();

    // ---- GEMM: gates = [x|h] @ [Wih|Whh]^T ----
    f32x4 acc[8] = {};
    for (int ks = 0; ks < 36; ++ks) {
        int mtile = mh * 4 + wave;
        half8 a = (ks < 20)
            ? *(const half8*)(x_sw + ((mtile * 20 + ks) * 64 + lane) * 8)
            : *(const half8*)(hprev_sw + ((mtile * 16 + (ks - 20)) * 64 + lane) * 8);
        half8 bv[8];
        #pragma unroll
        for (int jt = 0; jt < 8; ++jt) {
            int g = jt >> 1, u2 = jt & 1;
            int ntile = g * 32 + j * 2 + u2;
            bv[jt] = (ks < 20)
                ? *(const half8*)(wih_sw + ((ntile * 20 + ks) * 64 + lane) * 8)
                : *(const half8*)(whh_sw + ((ntile * 16 + (ks - 20)) * 64 + lane) * 8);
        }
        #pragma unroll
        for (int jt = 0; jt < 8; ++jt)
            acc[jt] = MFMA16(a, bv[jt], acc[jt]);
    }
    float bias[8];
    #pragma unroll
    for (int jt = 0; jt < 8; ++jt) {
        int g = jt >> 1, u2 = jt & 1;
        bias[jt] = dec_b[g * 512 + j * 32 + u2 * 16 + col];
    }
    #pragma unroll
    for (int r = 0; r < 4; ++r) {
        int lb = wave * 16 + quad * 4 + r;
        int bb = mh * 64 + lb;
        #pragma unroll
        for (int u2 = 0; u2 < 2; ++u2) {
            int hl = u2 * 16 + col, hcol = j * 32 + hl;
            float gi = acc[0 + u2][r] + bias[0 + u2];
            float gf = acc[2 + u2][r] + bias[2 + u2];
            float gg = acc[4 + u2][r] + bias[4 + u2];
            float go = acc[6 + u2][r] + bias[6 + u2];
            float ig = fsig(gi), fg = fsig(gf), g2 = ftanh(gg), og = fsig(go);
            float cv = fg * c_ws[bb * 512 + hcol] + ig * g2;
            c_ws[bb * 512 + hcol] = cv;
            float h = og * ftanh(cv);
            f16 h16 = (f16)h;
            int fidx = frag_idx(bb, hcol, 16);
            hnext_sw[fidx] = h16;
            hhist_sw[t * 65536 + fidx] = h16;
            hsl[lb][hl] = h16;
        }
    }
    // fused q-partials for next step (wave reads its own hsl rows)
    half8 aq = *(const half8*)(&hsl[wave * 16 + col][quad * 8]);
    for (int nt = 0; nt < 32; ++nt) {
        half8 bq = *(const half8*)(WhT_sw + ((nt * 16 + j) * 64 + lane) * 8);
        f32x4 q0 = {};
        q0 = MFMA16(aq, bq, q0);
        #pragma unroll
        for (int r = 0; r < 4; ++r)
            qpart[(j * 128 + mh * 64 + wave * 16 + quad * 4 + r) * 512 + nt * 16 + col] = q0[r];
    }
}

// ---------------------------------------------------------------------------
// K_logits: batched over all 127 steps (once).
// ---------------------------------------------------------------------------
__global__ __launch_bounds__(256) void k_logits(
    const f16* __restrict__ hhist_sw, const f16* __restrict__ outWT_sw,
    const float* __restrict__ out_b, float* __restrict__ out)
{
    int bt = blockIdx.x;
    int tid = threadIdx.x, wave = tid >> 6, lane = tid & 63;
    int col = lane & 15, quad = lane >> 4;
    f32x4 acc[2][8] = {};
    for (int ks = 0; ks < 16; ++ks) {
        half8 a[2];
        #pragma unroll
        for (int i = 0; i < 2; ++i)
            a[i] = *(const half8*)(hhist_sw + bt * 65536 + (((wave * 2 + i) * 16 + ks) * 64 + lane) * 8);
        half8 bv[8];
        #pragma unroll
        for (int jt = 0; jt < 8; ++jt)
            bv[jt] = *(const half8*)(outWT_sw + ((jt * 16 + ks) * 64 + lane) * 8);
        #pragma unroll
        for (int jt = 0; jt < 8; ++jt) {
            acc[0][jt] = MFMA16(a[0], bv[jt], acc[0][jt]);
            acc[1][jt] = MFMA16(a[1], bv[jt], acc[1][jt]);
        }
    }
    #pragma unroll
    for (int jt = 0; jt < 8; ++jt) {
        float bias = out_b[jt * 16 + col];
        #pragma unroll
        for (int i = 0; i < 2; ++i)
            #pragma unroll
            for (int r = 0; r < 4; ++r) {
                int br = wave * 32 + i * 16 + quad * 4 + r;
                out[br * 16384 + (bt + 1) * 128 + jt * 16 + col] = acc[i][jt][r] + bias;
            }
    }
}

// ---------------------------------------------------------------------------
extern "C" void kernel_launch(void* const* d_in, const int* in_sizes, int n_in,
                              void* d_out, int out_size, void* d_ws, size_t ws_size,
                              hipStream_t stream)
{
    (void)in_sizes; (void)n_in; (void)out_size;
    if (ws_size < 164000000) return;  // clean bail if workspace too small

    const int*   src     = (const int*)d_in[0];
    const int*   trg     = (const int*)d_in[1];
    const float* enc_emb = (const float*)d_in[2];
    const float* wihf    = (const float*)d_in[3];
    const float* whhf    = (const float*)d_in[4];
    const float* bf_     = (const float*)d_in[5];
    const float* wihb    = (const float*)d_in[6];
    const float* whhb    = (const float*)d_in[7];
    const float* bb_     = (const float*)d_in[8];
    const float* dec_emb = (const float*)d_in[9];
    const float* dec_wih = (const float*)d_in[10];
    const float* dec_whh = (const float*)d_in[11];
    const float* dec_b   = (const float*)d_in[12];
    const float* attn_W  = (const float*)d_in[13];
    const float* attn_b  = (const float*)d_in[14];
    const float* attn_v  = (const float*)d_in[15];
    const float* out_W   = (const float*)d_in[16];
    const float* out_b   = (const float*)d_in[17];
    float* out = (float*)d_out;

    char* p = (char*)d_ws;
    auto carve = [&](size_t n) { char* r = p; p += ((n + 255) & ~(size_t)255); return r; };
    f16*   enc_out   = (f16*)  carve(67108864);
    f16*   proj      = (f16*)  carve(67108864);
    f16*   WhT_sw    = (f16*)  carve(524288);
    f16*   WeT       = (f16*)  carve(524288);
    f16*   outWT_sw  = (f16*)  carve(131072);
    f16*   emb16     = (f16*)  carve(32768);
    f16*   wihf16    = (f16*)  carve(262144);
    f16*   wihb16    = (f16*)  carve(262144);
    f16*   whhf_sw   = (f16*)  carve(524288);
    f16*   whhb_sw   = (f16*)  carve(524288);
    f16*   decemb16  = (f16*)  carve(32768);
    f16*   decwih_sw = (f16*)  carve(2621440);
    f16*   decwhh_sw = (f16*)  carve(2097152);
    float* qpart     = (float*)carve(4194304);
    f16*   hdec0     = (f16*)  carve(131072);
    f16*   hdec1     = (f16*)  carve(131072);
    float* c_ws      = (float*)carve(262144);
    f16*   x_sw      = (f16*)  carve(163840);
    f16*   hhist_sw  = (f16*)  carve(16646144);
    f16*   xg_vocab  = (f16*)  carve(524288);
    float* part_m    = (float*)carve(2048);
    float* part_l    = (float*)carve(2048);
    float* part_ctx  = (float*)carve(524288);

    k_prep<<<14784, 256, 0, stream>>>(attn_W, out_W, enc_emb, wihf, wihb, whhf, whhb,
                                      dec_emb, dec_wih, dec_whh,
                                      WhT_sw, outWT_sw, whhf_sw, whhb_sw,
                                      decwih_sw, decwhh_sw, WeT, emb16,
                                      wihf16, wihb16, decemb16, out);
    k_vocab<<<16, 256, 0, stream>>>(emb16, wihf16, wihb16, bf_, bb_, xg_vocab);
    k_enc<<<16, 512, 0, stream>>>(src, xg_vocab, whhf_sw, whhb_sw, enc_out, hdec0, c_ws);
    k_proj<<<2048, 256, 0, stream>>>(enc_out, WeT, proj);
    k_qinit<<<16, 256, 0, stream>>>(hdec0, WhT_sw, qpart);
    for (int t = 0; t < 127; ++t) {
        k_att<<<256, 512, 0, stream>>>(proj, enc_out, qpart, attn_b, attn_v,
                                       trg, decemb16, x_sw, part_m, part_l,
                                       part_ctx, t);
        f16* hin  = (t & 1) ? hdec1 : hdec0;
        f16* hout = (t & 1) ? hdec0 : hdec1;
        k_gates<<<32, 256, 0, stream>>>(x_sw, hin, decwih_sw, decwhh_sw, dec_b,
                                        c_ws, hout, hhist_sw, WhT_sw, qpart,
                                        part_m, part_l, part_ctx, t);
    }
    k_logits<<<127, 256, 0, stream>>>(hhist_sw, outWT_sw, out_b, out);
}

// Round 11
// 13057.785 us; speedup vs baseline: 3.8982x; 1.0189x over previous
//
#include <hip/hip_runtime.h>

// ============================================================================
// Seq2Seq (bi-LSTM encoder + Bahdanau-attention LSTM decoder) on gfx950.
// fp32 in/out; fp16 internal (fp32 accum/state).
// R11 = R10 (13.30 ms) + int8 proj:
//   proj (scores-pass input, 67 MB/step of the 134 MB attention stream) is
//   stored as int8 x fixed scale -- 25% traffic cut on the BW-saturated
//   attention stream.  Error is averaged by tanh+dot+softmax before touching
//   state (predicted absmax ~1.3e-3 vs 3.9e-3 threshold).
// ============================================================================

typedef _Float16 f16;
typedef _Float16 half8 __attribute__((ext_vector_type(8)));
typedef float f32x4 __attribute__((ext_vector_type(4)));
typedef char char8v __attribute__((ext_vector_type(8)));

#define MFMA16(a, b, c) __builtin_amdgcn_mfma_f32_16x16x32_f16((a), (b), (c), 0, 0, 0)

#define PSCALE (2.5f / 127.f)      // int8 proj dequant scale
#define PINV   (127.f / 2.5f)      // quant scale

__device__ __forceinline__ float fsig(float x) {
    return __builtin_amdgcn_rcpf(1.f + __expf(-x));
}
__device__ __forceinline__ float ftanh(float x) {
    return 1.f - 2.f * __builtin_amdgcn_rcpf(1.f + __expf(2.f * x));
}
__device__ __forceinline__ int frag_idx(int m, int k, int KS) {
    return (((m >> 4) * KS + (k >> 5)) * 64 + (((k >> 3) & 3) * 16 + (m & 15))) * 8 + (k & 7);
}

// ---------------------------------------------------------------------------
// K0: one-shot: pack weights to fragment order (f32 -> f16), plain converts,
// zero out t=0 output row.
// ---------------------------------------------------------------------------
__global__ __launch_bounds__(256) void k_prep(
    const float* __restrict__ attn_W, const float* __restrict__ out_W,
    const float* __restrict__ enc_emb,
    const float* __restrict__ wihf, const float* __restrict__ wihb,
    const float* __restrict__ whhf, const float* __restrict__ whhb,
    const float* __restrict__ dec_emb, const float* __restrict__ dec_wih,
    const float* __restrict__ dec_whh,
    f16* __restrict__ WhT_sw, f16* __restrict__ outWT_sw,
    f16* __restrict__ whhf_sw, f16* __restrict__ whhb_sw,
    f16* __restrict__ decwih_sw, f16* __restrict__ decwhh_sw,
    f16* __restrict__ WeT, f16* __restrict__ emb16,
    f16* __restrict__ wihf16, f16* __restrict__ wihb16,
    f16* __restrict__ decemb16, float* __restrict__ out)
{
    long i = (long)blockIdx.x * 256 + threadIdx.x;
    if (i >= 3784704L) return;
    long idx = i;
    if (idx < 262144) {  // WhT_sw: N=512(e) x K=512(d)
        int j = idx & 7, lane = (idx >> 3) & 63, c = lane & 15, q = lane >> 4;
        int ks = (idx >> 9) & 15, nt = idx >> 13;
        WhT_sw[idx] = (f16)attn_W[(ks * 32 + q * 8 + j) * 512 + nt * 16 + c];
        return;
    }
    idx -= 262144;
    if (idx < 65536) {   // outWT_sw: N=128(v) x K=512(d)
        int j = idx & 7, lane = (idx >> 3) & 63, c = lane & 15, q = lane >> 4;
        int ks = (idx >> 9) & 15, nt = idx >> 13;
        outWT_sw[idx] = (f16)out_W[(ks * 32 + q * 8 + j) * 128 + nt * 16 + c];
        return;
    }
    idx -= 65536;
    if (idx < 262144) {  // whhf_sw: N=1024 x K=256
        int j = idx & 7, lane = (idx >> 3) & 63, c = lane & 15, q = lane >> 4;
        int ks = (idx >> 9) & 7, nt = idx >> 12;
        whhf_sw[idx] = (f16)whhf[(nt * 16 + c) * 256 + ks * 32 + q * 8 + j];
        return;
    }
    idx -= 262144;
    if (idx < 262144) {  // whhb_sw
        int j = idx & 7, lane = (idx >> 3) & 63, c = lane & 15, q = lane >> 4;
        int ks = (idx >> 9) & 7, nt = idx >> 12;
        whhb_sw[idx] = (f16)whhb[(nt * 16 + c) * 256 + ks * 32 + q * 8 + j];
        return;
    }
    idx -= 262144;
    if (idx < 1310720) { // decwih_sw: N=2048 x K=640
        int j = idx & 7, lane = (idx >> 3) & 63, c = lane & 15, q = lane >> 4;
        int r2 = idx >> 9; int ks = r2 % 20, nt = r2 / 20;
        decwih_sw[idx] = (f16)dec_wih[(nt * 16 + c) * 640 + ks * 32 + q * 8 + j];
        return;
    }
    idx -= 1310720;
    if (idx < 1048576) { // decwhh_sw: N=2048 x K=512
        int j = idx & 7, lane = (idx >> 3) & 63, c = lane & 15, q = lane >> 4;
        int ks = (idx >> 9) & 15, nt = idx >> 13;
        decwhh_sw[idx] = (f16)dec_whh[(nt * 16 + c) * 512 + ks * 32 + q * 8 + j];
        return;
    }
    idx -= 1048576;
    if (idx < 262144) { int e = idx >> 9, d = idx & 511; WeT[idx] = (f16)attn_W[(512 + d) * 512 + e]; return; }
    idx -= 262144;
    if (idx < 16384)  { emb16[idx] = (f16)enc_emb[idx]; return; }
    idx -= 16384;
    if (idx < 131072) { wihf16[idx] = (f16)wihf[idx]; return; }
    idx -= 131072;
    if (idx < 131072) { wihb16[idx] = (f16)wihb[idx]; return; }
    idx -= 131072;
    if (idx < 16384)  { decemb16[idx] = (f16)dec_emb[idx]; return; }
    idx -= 16384;
    if (idx < 16384)  { int b = idx >> 7, v = idx & 127; out[b * 16384 + v] = 0.f; return; }
}

// ---------------------------------------------------------------------------
// K_vocab: xg_vocab[v][n] = emb[v] @ [Wih_f|Wih_b]^T + [b_f|b_b] (once).
// ---------------------------------------------------------------------------
__global__ __launch_bounds__(256) void k_vocab(
    const f16* __restrict__ emb, const f16* __restrict__ wihf,
    const f16* __restrict__ wihb, const float* __restrict__ bf_,
    const float* __restrict__ bb_, f16* __restrict__ xg_vocab)
{
    int bn = blockIdx.x;
    int tid = threadIdx.x, wave = tid >> 6, lane = tid & 63;
    int col = lane & 15, quad = lane >> 4;
    int wr = wave >> 1, wc = wave & 1;

    f32x4 acc[4][4] = {};
    for (int ks = 0; ks < 4; ++ks) {
        int k0 = ks * 32 + quad * 8;
        half8 a[4], bfr[4];
        for (int i = 0; i < 4; ++i)
            a[i] = *(const half8*)(emb + (wr * 64 + i * 16 + col) * 128 + k0);
        for (int j = 0; j < 4; ++j) {
            int n = bn * 128 + wc * 64 + j * 16 + col;
            const f16* wp = (n < 1024) ? (wihf + n * 128) : (wihb + (n - 1024) * 128);
            bfr[j] = *(const half8*)(wp + k0);
        }
        for (int i = 0; i < 4; ++i)
            for (int j = 0; j < 4; ++j)
                acc[i][j] = MFMA16(a[i], bfr[j], acc[i][j]);
    }
    for (int j = 0; j < 4; ++j) {
        int n = bn * 128 + wc * 64 + j * 16 + col;
        float bias = (n < 1024) ? bf_[n] : bb_[n - 1024];
        for (int i = 0; i < 4; ++i) {
            int vbase = wr * 64 + i * 16 + quad * 4;
            for (int r = 0; r < 4; ++r)
                xg_vocab[(vbase + r) * 2048 + n] = (f16)(acc[i][j][r] + bias);
        }
    }
}

// ---------------------------------------------------------------------------
// K_enc: encoder scan, 16 persistent blocks (2 dir x 8 batch-groups of 16),
// 512 threads.  Gate-0/1 Whh fragments live in VGPRs across the whole
// 512-step loop; gates 2/3 stream from L2.  (R10 -- known correct)
// ---------------------------------------------------------------------------
__global__ __launch_bounds__(512, 2) void k_enc(
    const int* __restrict__ src, const f16* __restrict__ xg_vocab,
    const f16* __restrict__ whhf_sw, const f16* __restrict__ whhb_sw,
    f16* __restrict__ enc_out, f16* __restrict__ hdec0, float* __restrict__ c_ws)
{
    int blk = blockIdx.x;
    int dir = blk >> 3, bbase = (blk & 7) * 16;
    int tid = threadIdx.x, wave = tid >> 6, lane = tid & 63;
    int col = lane & 15, quad = lane >> 4;
    const f16* whh = dir ? whhb_sw : whhf_sw;

    __shared__ f16 hb[16][264];
    __shared__ f16 xvb[16][1032];
    __shared__ int stok[16];
    for (int z = tid; z < 16 * 264; z += 512) ((f16*)hb)[z] = (f16)0.f;
    float cc[2][4] = {};

    half8 bst[32];
    #pragma unroll
    for (int g = 0; g < 2; ++g)
        #pragma unroll
        for (int nt = 0; nt < 2; ++nt)
            #pragma unroll
            for (int kk = 0; kk < 8; ++kk) {
                int tile = g * 16 + wave * 2 + nt;
                bst[(g * 2 + nt) * 8 + kk] =
                    *(const half8*)(whh + ((tile * 8 + kk) * 64 + lane) * 8);
            }
    __syncthreads();

    for (int t = 0; t < 512; ++t) {
        int ts = dir ? (511 - t) : t;
        if (tid < 16) stok[tid] = src[(bbase + tid) * 512 + ts];
        half8 a[8];
        #pragma unroll
        for (int kk = 0; kk < 8; ++kk)
            a[kk] = *(const half8*)(&hb[col][kk * 32 + quad * 8]);
        __syncthreads();

        #pragma unroll
        for (int it = 0; it < 4; ++it) {
            int cnk = it * 512 + tid;
            int row = cnk >> 7, off = (cnk & 127) * 8;
            *(half8*)(&xvb[row][off]) =
                *(const half8*)(xg_vocab + stok[row] * 2048 + dir * 1024 + off);
        }

        f32x4 acc[4][2] = {};
        #pragma unroll
        for (int kk = 0; kk < 8; ++kk) {
            half8 bv[4];
            #pragma unroll
            for (int g = 2; g < 4; ++g)
                #pragma unroll
                for (int nt = 0; nt < 2; ++nt) {
                    int tile = g * 16 + wave * 2 + nt;
                    bv[(g - 2) * 2 + nt] =
                        *(const half8*)(whh + ((tile * 8 + kk) * 64 + lane) * 8);
                }
            #pragma unroll
            for (int g = 0; g < 2; ++g)
                #pragma unroll
                for (int nt = 0; nt < 2; ++nt)
                    acc[g][nt] = MFMA16(a[kk], bst[(g * 2 + nt) * 8 + kk], acc[g][nt]);
            #pragma unroll
            for (int g = 2; g < 4; ++g)
                #pragma unroll
                for (int nt = 0; nt < 2; ++nt)
                    acc[g][nt] = MFMA16(a[kk], bv[(g - 2) * 2 + nt], acc[g][nt]);
        }
        __syncthreads();

        #pragma unroll
        for (int nt = 0; nt < 2; ++nt) {
            int hcol = wave * 32 + nt * 16 + col;
            #pragma unroll
            for (int r = 0; r < 4; ++r) {
                int b = quad * 4 + r;
                float gi = (float)xvb[b][0 * 256 + hcol] + acc[0][nt][r];
                float gf = (float)xvb[b][1 * 256 + hcol] + acc[1][nt][r];
                float gg = (float)xvb[b][2 * 256 + hcol] + acc[2][nt][r];
                float go = (float)xvb[b][3 * 256 + hcol] + acc[3][nt][r];
                float ig = fsig(gi), fg = fsig(gf), g2 = ftanh(gg), og = fsig(go);
                float cv = fg * cc[nt][r] + ig * g2;
                cc[nt][r] = cv;
                float h = og * ftanh(cv);
                f16 h16 = (f16)h;
                hb[b][hcol] = h16;
                enc_out[((size_t)(bbase + b) * 512 + ts) * 512 + dir * 256 + hcol] = h16;
            }
        }
        __syncthreads();
    }
    #pragma unroll
    for (int nt = 0; nt < 2; ++nt) {
        int hcol = wave * 32 + nt * 16 + col;
        #pragma unroll
        for (int r = 0; r < 4; ++r) {
            int b = quad * 4 + r;
            int m = bbase + b, k = dir * 256 + hcol;
            hdec0[frag_idx(m, k, 16)] = hb[b][hcol];
            c_ws[m * 512 + k] = cc[nt][r];
        }
    }
}

// ---------------------------------------------------------------------------
// K_proj: enc_proj = enc_out @ We (once).  R11: writes int8 (fixed scale).
// ---------------------------------------------------------------------------
__global__ __launch_bounds__(256) void k_proj(
    const f16* __restrict__ enc_out, const f16* __restrict__ WeT,
    char* __restrict__ proj8)
{
    int blk = blockIdx.x;
    int bm = blk & 511, bn = blk >> 9;
    int tid = threadIdx.x, wave = tid >> 6, lane = tid & 63;
    int col = lane & 15, quad = lane >> 4;
    int wr = wave >> 1, wc = wave & 1;

    f32x4 acc[4][4] = {};
    for (int ks = 0; ks < 16; ++ks) {
        int k0 = ks * 32 + quad * 8;
        half8 a[4], bfr[4];
        for (int i = 0; i < 4; ++i) {
            int m = bm * 128 + wr * 64 + i * 16 + col;
            a[i] = *(const half8*)(enc_out + (size_t)m * 512 + k0);
        }
        for (int j = 0; j < 4; ++j) {
            int n = bn * 128 + wc * 64 + j * 16 + col;
            bfr[j] = *(const half8*)(WeT + n * 512 + k0);
        }
        for (int i = 0; i < 4; ++i)
            for (int j = 0; j < 4; ++j)
                acc[i][j] = MFMA16(a[i], bfr[j], acc[i][j]);
    }
    for (int j = 0; j < 4; ++j) {
        int n = bn * 128 + wc * 64 + j * 16 + col;
        for (int i = 0; i < 4; ++i) {
            int mbase = bm * 128 + wr * 64 + i * 16 + quad * 4;
            for (int r = 0; r < 4; ++r) {
                float v = acc[i][j][r] * PINV;
                int q = (int)rintf(v);
                q = (q > 127) ? 127 : ((q < -127) ? -127 : q);
                proj8[(size_t)(mbase + r) * 512 + n] = (char)q;
            }
        }
    }
}

// ---------------------------------------------------------------------------
// K_qinit: initial q-partials (once).
// ---------------------------------------------------------------------------
__global__ __launch_bounds__(256) void k_qinit(
    const f16* __restrict__ h0_sw, const f16* __restrict__ WhT_sw,
    float* __restrict__ qpart)
{
    int j = blockIdx.x;
    int tid = threadIdx.x, wave = tid >> 6, lane = tid & 63;
    int col = lane & 15, quad = lane >> 4;
    half8 a[2];
    #pragma unroll
    for (int i = 0; i < 2; ++i)
        a[i] = *(const half8*)(h0_sw + (((wave * 2 + i) * 16 + j) * 64 + lane) * 8);
    for (int nt = 0; nt < 32; ++nt) {
        half8 bfr = *(const half8*)(WhT_sw + ((nt * 16 + j) * 64 + lane) * 8);
        f32x4 q0 = {}, q1 = {};
        q0 = MFMA16(a[0], bfr, q0);
        q1 = MFMA16(a[1], bfr, q1);
        #pragma unroll
        for (int r = 0; r < 4; ++r) {
            qpart[(j * 128 + wave * 32 + quad * 4 + r) * 512 + nt * 16 + col] = q0[r];
            qpart[(j * 128 + wave * 32 + 16 + quad * 4 + r) * 512 + nt * 16 + col] = q1[r];
        }
    }
}

// ---------------------------------------------------------------------------
// K_att (per step): 256 blocks x 512 thr; block = (b, sh) over 256 s-rows.
// Two-pass shape: scores pass (8-deep, int8 proj decode inline) ->
// block-local softmax stats -> ctx pass (8-deep half8) -> unnormalized
// partial (M, l, ctx[512]).  No atomics/fences.
// ---------------------------------------------------------------------------
__global__ __launch_bounds__(512) void k_att(
    const char* __restrict__ proj8, const f16* __restrict__ enc_out,
    const float* __restrict__ qpart, const float* __restrict__ attn_b,
    const float* __restrict__ attn_v, const int* __restrict__ trg,
    const f16* __restrict__ dec_emb, f16* __restrict__ x_sw,
    float* __restrict__ part_m, float* __restrict__ part_l,
    float* __restrict__ part_ctx, int t)
{
    int blk = blockIdx.x;
    int b = blk >> 1, sh = blk & 1;
    int tid = threadIdx.x, wave = tid >> 6, lane = tid & 63;
    __shared__ float q[512];
    __shared__ float sc[256];
    __shared__ float ctxred[8][512];
    __shared__ float wred[8], wred2[8];

    {
        float s = attn_b[tid];
        #pragma unroll
        for (int jj = 0; jj < 16; ++jj) s += qpart[(jj * 128 + b) * 512 + tid];
        q[tid] = s;
    }
    __syncthreads();

    float qreg[8], vreg[8];
    #pragma unroll
    for (int u = 0; u < 8; ++u) {
        int e = lane * 8 + u;
        qreg[u] = q[e];
        vreg[u] = attn_v[e];
    }
    int sbase = sh * 256;
    // scores: wave w handles local rows sl = z8*8 + w; 8-deep batching
    for (int ib = 0; ib < 4; ++ib) {
        char8v p[8];
        #pragma unroll
        for (int z = 0; z < 8; ++z) {
            int sl = (ib * 8 + z) * 8 + wave;
            p[z] = *(const char8v*)(proj8 + ((size_t)b * 512 + sbase + sl) * 512 + lane * 8);
        }
        #pragma unroll
        for (int z = 0; z < 8; ++z) {
            int sl = (ib * 8 + z) * 8 + wave;
            float part = 0.f;
            #pragma unroll
            for (int u = 0; u < 8; ++u)
                part += vreg[u] * ftanh(fmaf((float)p[z][u], PSCALE, qreg[u]));
            #pragma unroll
            for (int o = 32; o; o >>= 1) part += __shfl_xor(part, o);
            if (lane == 0) sc[sl] = part;
        }
    }
    __syncthreads();

    // block-local softmax stats over 256 rows
    float s0 = (tid < 256) ? sc[tid] : -__builtin_inff();
    float mv = s0;
    #pragma unroll
    for (int o = 32; o; o >>= 1) mv = fmaxf(mv, __shfl_xor(mv, o));
    if (lane == 0) wred[wave] = mv;
    __syncthreads();
    float M = wred[0];
    #pragma unroll
    for (int w = 1; w < 8; ++w) M = fmaxf(M, wred[w]);
    float e0 = (tid < 256) ? __expf(s0 - M) : 0.f;
    if (tid < 256) sc[tid] = e0;
    float sm = e0;
    #pragma unroll
    for (int o = 32; o; o >>= 1) sm += __shfl_xor(sm, o);
    if (lane == 0) wred2[wave] = sm;
    __syncthreads();
    float lb = wred2[0];
    #pragma unroll
    for (int w = 1; w < 8; ++w) lb += wred2[w];

    // ctx: wave owns same 32 local rows; 8-deep half8 batching
    float a8[8] = {};
    for (int ib = 0; ib < 4; ++ib) {
        half8 ev[8];
        float wgt[8];
        #pragma unroll
        for (int z = 0; z < 8; ++z) {
            int sl = (ib * 8 + z) * 8 + wave;
            ev[z] = *(const half8*)(enc_out + ((size_t)b * 512 + sbase + sl) * 512 + lane * 8);
            wgt[z] = sc[sl];
        }
        #pragma unroll
        for (int z = 0; z < 8; ++z)
            #pragma unroll
            for (int u = 0; u < 8; ++u) a8[u] += wgt[z] * (float)ev[z][u];
    }
    #pragma unroll
    for (int u = 0; u < 8; ++u) ctxred[wave][lane * 8 + u] = a8[u];
    __syncthreads();
    float cp = 0.f;
    #pragma unroll
    for (int w = 0; w < 8; ++w) cp += ctxred[w][tid];
    part_ctx[(size_t)blk * 512 + tid] = cp;
    if (tid == 0) { part_m[blk] = M; part_l[blk] = lb; }

    if (sh == 0 && tid < 128) {
        int tok = trg[b * 128 + t];
        x_sw[frag_idx(b, tid, 20)] = dec_emb[tok * 128 + tid];
    }
}

// ---------------------------------------------------------------------------
// K_gates (per step): 32 blocks = (j n-slice, mh m-half).  Prologue combines
// the two softmax partials for THIS block's 64 batch rows into x_sw.
// Then the proven GEMM + in-lane LSTM + fused q-partial GEMM.
// ---------------------------------------------------------------------------
__global__ __launch_bounds__(256) void k_gates(
    f16* __restrict__ x_sw, const f16* __restrict__ hprev_sw,
    const f16* __restrict__ wih_sw, const f16* __restrict__ whh_sw,
    const float* __restrict__ dec_b, float* __restrict__ c_ws,
    f16* __restrict__ hnext_sw, f16* __restrict__ hhist_sw,
    const f16* __restrict__ WhT_sw, float* __restrict__ qpart,
    const float* __restrict__ part_m, const float* __restrict__ part_l,
    const float* __restrict__ part_ctx, int t)
{
    int jb = blockIdx.x;
    int j = jb >> 1, mh = jb & 1;
    int tid = threadIdx.x, wave = tid >> 6, lane = tid & 63;
    int col = lane & 15, quad = lane >> 4;
    __shared__ f16 hsl[64][40];
    __shared__ float gm[64][2];

    if (tid < 64) {
        int bb = mh * 64 + tid;
        float m0 = part_m[bb * 2 + 0], m1 = part_m[bb * 2 + 1];
        float l0 = part_l[bb * 2 + 0], l1 = part_l[bb * 2 + 1];
        float M = fmaxf(m0, m1);
        float g0 = __expf(m0 - M), g1 = __expf(m1 - M);
        float inv = 1.f / (g0 * l0 + g1 * l1);
        gm[tid][0] = g0 * inv;
        gm[tid][1] = g1 * inv;
    }
    __syncthreads();
    for (int z = tid; z < 32768; z += 256) {
        int lr = z >> 9, d = z & 511;
        int bb = mh * 64 + lr;
        float c = gm[lr][0] * part_ctx[(size_t)(bb * 2 + 0) * 512 + d]
                + gm[lr][1] * part_ctx[(size_t)(bb * 2 + 1) * 512 + d];
        x_sw[frag_idx(bb, 128 + d, 20)] = (f16)c;
    }
    __syncthreads();

    f32x4 acc[8] = {};
    for (int ks = 0; ks < 36; ++ks) {
        int mtile = mh * 4 + wave;
        half8 a = (ks < 20)
            ? *(const half8*)(x_sw + ((mtile * 20 + ks) * 64 + lane) * 8)
            : *(const half8*)(hprev_sw + ((mtile * 16 + (ks - 20)) * 64 + lane) * 8);
        half8 bv[8];
        #pragma unroll
        for (int jt = 0; jt < 8; ++jt) {
            int g = jt >> 1, u2 = jt & 1;
            int ntile = g * 32 + j * 2 + u2;
            bv[jt] = (ks < 20)
                ? *(const half8*)(wih_sw + ((ntile * 20 + ks) * 64 + lane) * 8)
                : *(const half8*)(whh_sw + ((ntile * 16 + (ks - 20)) * 64 + lane) * 8);
        }
        #pragma unroll
        for (int jt = 0; jt < 8; ++jt)
            acc[jt] = MFMA16(a, bv[jt], acc[jt]);
    }
    float bias[8];
    #pragma unroll
    for (int jt = 0; jt < 8; ++jt) {
        int g = jt >> 1, u2 = jt & 1;
        bias[jt] = dec_b[g * 512 + j * 32 + u2 * 16 + col];
    }
    #pragma unroll
    for (int r = 0; r < 4; ++r) {
        int lb = wave * 16 + quad * 4 + r;
        int bb = mh * 64 + lb;
        #pragma unroll
        for (int u2 = 0; u2 < 2; ++u2) {
            int hl = u2 * 16 + col, hcol = j * 32 + hl;
            float gi = acc[0 + u2][r] + bias[0 + u2];
            float gf = acc[2 + u2][r] + bias[2 + u2];
            float gg = acc[4 + u2][r] + bias[4 + u2];
            float go = acc[6 + u2][r] + bias[6 + u2];
            float ig = fsig(gi), fg = fsig(gf), g2 = ftanh(gg), og = fsig(go);
            float cv = fg * c_ws[bb * 512 + hcol] + ig * g2;
            c_ws[bb * 512 + hcol] = cv;
            float h = og * ftanh(cv);
            f16 h16 = (f16)h;
            int fidx = frag_idx(bb, hcol, 16);
            hnext_sw[fidx] = h16;
            hhist_sw[t * 65536 + fidx] = h16;
            hsl[lb][hl] = h16;
        }
    }
    half8 aq = *(const half8*)(&hsl[wave * 16 + col][quad * 8]);
    for (int nt = 0; nt < 32; ++nt) {
        half8 bq = *(const half8*)(WhT_sw + ((nt * 16 + j) * 64 + lane) * 8);
        f32x4 q0 = {};
        q0 = MFMA16(aq, bq, q0);
        #pragma unroll
        for (int r = 0; r < 4; ++r)
            qpart[(j * 128 + mh * 64 + wave * 16 + quad * 4 + r) * 512 + nt * 16 + col] = q0[r];
    }
}

// ---------------------------------------------------------------------------
// K_logits: batched over all 127 steps (once).
// ---------------------------------------------------------------------------
__global__ __launch_bounds__(256) void k_logits(
    const f16* __restrict__ hhist_sw, const f16* __restrict__ outWT_sw,
    const float* __restrict__ out_b, float* __restrict__ out)
{
    int bt = blockIdx.x;
    int tid = threadIdx.x, wave = tid >> 6, lane = tid & 63;
    int col = lane & 15, quad = lane >> 4;
    f32x4 acc[2][8] = {};
    for (int ks = 0; ks < 16; ++ks) {
        half8 a[2];
        #pragma unroll
        for (int i = 0; i < 2; ++i)
            a[i] = *(const half8*)(hhist_sw + bt * 65536 + (((wave * 2 + i) * 16 + ks) * 64 + lane) * 8);
        half8 bv[8];
        #pragma unroll
        for (int jt = 0; jt < 8; ++jt)
            bv[jt] = *(const half8*)(outWT_sw + ((jt * 16 + ks) * 64 + lane) * 8);
        #pragma unroll
        for (int jt = 0; jt < 8; ++jt) {
            acc[0][jt] = MFMA16(a[0], bv[jt], acc[0][jt]);
            acc[1][jt] = MFMA16(a[1], bv[jt], acc[1][jt]);
        }
    }
    #pragma unroll
    for (int jt = 0; jt < 8; ++jt) {
        float bias = out_b[jt * 16 + col];
        #pragma unroll
        for (int i = 0; i < 2; ++i)
            #pragma unroll
            for (int r = 0; r < 4; ++r) {
                int br = wave * 32 + i * 16 + quad * 4 + r;
                out[br * 16384 + (bt + 1) * 128 + jt * 16 + col] = acc[i][jt][r] + bias;
            }
    }
}

// ---------------------------------------------------------------------------
extern "C" void kernel_launch(void* const* d_in, const int* in_sizes, int n_in,
                              void* d_out, int out_size, void* d_ws, size_t ws_size,
                              hipStream_t stream)
{
    (void)in_sizes; (void)n_in; (void)out_size;
    if (ws_size < 130000000) return;  // clean bail if workspace too small

    const int*   src     = (const int*)d_in[0];
    const int*   trg     = (const int*)d_in[1];
    const float* enc_emb = (const float*)d_in[2];
    const float* wihf    = (const float*)d_in[3];
    const float* whhf    = (const float*)d_in[4];
    const float* bf_     = (const float*)d_in[5];
    const float* wihb    = (const float*)d_in[6];
    const float* whhb    = (const float*)d_in[7];
    const float* bb_     = (const float*)d_in[8];
    const float* dec_emb = (const float*)d_in[9];
    const float* dec_wih = (const float*)d_in[10];
    const float* dec_whh = (const float*)d_in[11];
    const float* dec_b   = (const float*)d_in[12];
    const float* attn_W  = (const float*)d_in[13];
    const float* attn_b  = (const float*)d_in[14];
    const float* attn_v  = (const float*)d_in[15];
    const float* out_W   = (const float*)d_in[16];
    const float* out_b   = (const float*)d_in[17];
    float* out = (float*)d_out;

    char* p = (char*)d_ws;
    auto carve = [&](size_t n) { char* r = p; p += ((n + 255) & ~(size_t)255); return r; };
    f16*   enc_out   = (f16*)  carve(67108864);
    char*  proj8     = (char*) carve(33554432);   // 65536 x 512 int8
    f16*   WhT_sw    = (f16*)  carve(524288);
    f16*   WeT       = (f16*)  carve(524288);
    f16*   outWT_sw  = (f16*)  carve(131072);
    f16*   emb16     = (f16*)  carve(32768);
    f16*   wihf16    = (f16*)  carve(262144);
    f16*   wihb16    = (f16*)  carve(262144);
    f16*   whhf_sw   = (f16*)  carve(524288);
    f16*   whhb_sw   = (f16*)  carve(524288);
    f16*   decemb16  = (f16*)  carve(32768);
    f16*   decwih_sw = (f16*)  carve(2621440);
    f16*   decwhh_sw = (f16*)  carve(2097152);
    float* qpart     = (float*)carve(4194304);
    f16*   hdec0     = (f16*)  carve(131072);
    f16*   hdec1     = (f16*)  carve(131072);
    float* c_ws      = (float*)carve(262144);
    f16*   x_sw      = (f16*)  carve(163840);
    f16*   hhist_sw  = (f16*)  carve(16646144);
    f16*   xg_vocab  = (f16*)  carve(524288);
    float* part_m    = (float*)carve(2048);
    float* part_l    = (float*)carve(2048);
    float* part_ctx  = (float*)carve(524288);

    k_prep<<<14784, 256, 0, stream>>>(attn_W, out_W, enc_emb, wihf, wihb, whhf, whhb,
                                      dec_emb, dec_wih, dec_whh,
                                      WhT_sw, outWT_sw, whhf_sw, whhb_sw,
                                      decwih_sw, decwhh_sw, WeT, emb16,
                                      wihf16, wihb16, decemb16, out);
    k_vocab<<<16, 256, 0, stream>>>(emb16, wihf16, wihb16, bf_, bb_, xg_vocab);
    k_enc<<<16, 512, 0, stream>>>(src, xg_vocab, whhf_sw, whhb_sw, enc_out, hdec0, c_ws);
    k_proj<<<2048, 256, 0, stream>>>(enc_out, WeT, proj8);
    k_qinit<<<16, 256, 0, stream>>>(hdec0, WhT_sw, qpart);
    for (int t = 0; t < 127; ++t) {
        k_att<<<256, 512, 0, stream>>>(proj8, enc_out, qpart, attn_b, attn_v,
                                       trg, decemb16, x_sw, part_m, part_l,
                                       part_ctx, t);
        f16* hin  = (t & 1) ? hdec1 : hdec0;
        f16* hout = (t & 1) ? hdec0 : hdec1;
        k_gates<<<32, 256, 0, stream>>>(x_sw, hin, decwih_sw, decwhh_sw, dec_b,
                                        c_ws, hout, hhist_sw, WhT_sw, qpart,
                                        part_m, part_l, part_ctx, t);
    }
    k_logits<<<127, 256, 0, stream>>>(hhist_sw, outWT_sw, out_b, out);
}